// Round 2
// baseline (2501.559 us; speedup 1.0000x reference)
//
#include <hip/hip_runtime.h>

typedef __attribute__((ext_vector_type(4))) float floatx4;

constexpr int NB = 4;     // batch
constexpr int NL = 1024;  // seq len
constexpr int ND = 1024;  // d_model
constexpr int NH = 16;    // heads
constexpr int NDK = 64;   // d_k = d_v

// ---------------------------------------------------------------------------
// K1: per-head input projection.  OUT(H,B,L,64) = X(B*L,1024) @ W(H,1024,64)
// 128x128 output tile per block, KT=16, 8x8 per-thread fp32 accum.
// ---------------------------------------------------------------------------
__global__ __launch_bounds__(256) void k_proj(const float* __restrict__ Xin,
                                              const float* __restrict__ W,
                                              float* __restrict__ OUT){
  __shared__ float As[16][128];
  __shared__ float Bs[16][128];
  const int tid = threadIdx.x;
  const int row0 = blockIdx.y * 128, col0 = blockIdx.x * 128;
  const int ty = tid >> 4, tx = tid & 15;
  float acc[8][8];
  #pragma unroll
  for (int i = 0; i < 8; i++)
    #pragma unroll
    for (int j = 0; j < 8; j++) acc[i][j] = 0.f;

  for (int k0 = 0; k0 < ND; k0 += 16){
    { // A tile: 128 rows x 16 k
      int r = tid >> 1, ch = tid & 1;
      const float* src = Xin + (size_t)(row0 + r) * ND + k0 + ch * 8;
      floatx4 v0 = *(const floatx4*)(src);
      floatx4 v1 = *(const floatx4*)(src + 4);
      #pragma unroll
      for (int e = 0; e < 4; e++){ As[ch*8 + e][r] = v0[e]; As[ch*8 + 4 + e][r] = v1[e]; }
    }
    { // B tile: 16 k x 128 cols (col c -> head c/64, dk c%64)
      int kk = tid >> 4, cc = tid & 15;
      int c = col0 + cc * 8;
      int h = c >> 6, dk = c & 63;
      const float* src = W + ((size_t)h * ND + (k0 + kk)) * NDK + dk;
      floatx4 v0 = *(const floatx4*)(src);
      floatx4 v1 = *(const floatx4*)(src + 4);
      #pragma unroll
      for (int e = 0; e < 4; e++){ Bs[kk][cc*8 + e] = v0[e]; Bs[kk][cc*8 + 4 + e] = v1[e]; }
    }
    __syncthreads();
    #pragma unroll
    for (int kk = 0; kk < 16; kk++){
      float a[8], bq[8];
      #pragma unroll
      for (int i = 0; i < 8; i++) a[i] = As[kk][ty * 8 + i];
      #pragma unroll
      for (int j = 0; j < 8; j++) bq[j] = Bs[kk][tx * 8 + j];
      #pragma unroll
      for (int i = 0; i < 8; i++)
        #pragma unroll
        for (int j = 0; j < 8; j++) acc[i][j] += a[i] * bq[j];
    }
    __syncthreads();
  }
  #pragma unroll
  for (int i = 0; i < 8; i++){
    int r = row0 + ty * 8 + i;
    int bb = r >> 10, l = r & 1023;
    int c0 = col0 + tx * 8;
    int h = c0 >> 6, dk = c0 & 63;
    float* dst = OUT + (((size_t)h * NB + bb) * NL + l) * NDK + dk;
    floatx4 o0, o1;
    #pragma unroll
    for (int j = 0; j < 4; j++){ o0[j] = acc[i][j]; o1[j] = acc[i][4 + j]; }
    *(floatx4*)(dst) = o0;
    *(floatx4*)(dst + 4) = o1;
  }
}

// ---------------------------------------------------------------------------
// K2a: scores = QH @ KH^T / 32, mask, row softmax -> ATT (fp32, part of d_out)
// One block handles one (h,b) and 8 query rows; each thread owns 4 s-columns.
// ---------------------------------------------------------------------------
__global__ __launch_bounds__(256) void k_scores(const float* __restrict__ QH,
                                                const float* __restrict__ KH,
                                                const int* __restrict__ MASK,
                                                float* __restrict__ ATT){
  const int bid = blockIdx.x;
  const int hb = bid >> 7;      // h*NB + b
  const int qt = bid & 127;
  const int b = hb & 3;
  const int l0 = qt * 8;
  const int tid = threadIdx.x;
  __shared__ float Q[8][64];
  __shared__ float red[8][4];
  if (tid < 64){
    int r = tid >> 3, ch = tid & 7;
    const float* src = QH + ((size_t)hb * NL + l0 + r) * NDK + ch * 8;
    floatx4 v0 = *(const floatx4*)(src);
    floatx4 v1 = *(const floatx4*)(src + 4);
    #pragma unroll
    for (int e = 0; e < 4; e++){ Q[r][ch*8 + e] = v0[e]; Q[r][ch*8 + 4 + e] = v1[e]; }
  }
  __syncthreads();

  float sc[8][4];
  #pragma unroll
  for (int j = 0; j < 4; j++){
    int s = tid + j * 256;
    float a[8] = {0.f,0.f,0.f,0.f,0.f,0.f,0.f,0.f};
    const float* krow = KH + ((size_t)hb * NL + s) * NDK;
    #pragma unroll
    for (int kc = 0; kc < 16; kc++){
      floatx4 kv = *(const floatx4*)(krow + kc * 4);
      #pragma unroll
      for (int qq = 0; qq < 8; qq++){
        a[qq] += kv[0] * Q[qq][kc*4 + 0] + kv[1] * Q[qq][kc*4 + 1]
               + kv[2] * Q[qq][kc*4 + 2] + kv[3] * Q[qq][kc*4 + 3];
      }
    }
    #pragma unroll
    for (int qq = 0; qq < 8; qq++){
      int m = MASK[((size_t)b * NL + l0 + qq) * NL + s];
      sc[qq][j] = m ? -1e9f : a[qq] * (1.0f / 32.0f);
    }
  }

  const int lane = tid & 63, wv = tid >> 6;
  float mx[8];
  #pragma unroll
  for (int qq = 0; qq < 8; qq++){
    float m = fmaxf(fmaxf(sc[qq][0], sc[qq][1]), fmaxf(sc[qq][2], sc[qq][3]));
    #pragma unroll
    for (int off = 32; off; off >>= 1) m = fmaxf(m, __shfl_xor(m, off));
    if (lane == 0) red[qq][wv] = m;
  }
  __syncthreads();
  #pragma unroll
  for (int qq = 0; qq < 8; qq++)
    mx[qq] = fmaxf(fmaxf(red[qq][0], red[qq][1]), fmaxf(red[qq][2], red[qq][3]));
  __syncthreads();

  #pragma unroll
  for (int qq = 0; qq < 8; qq++){
    float s_ = 0.f;
    #pragma unroll
    for (int j = 0; j < 4; j++){ sc[qq][j] = __expf(sc[qq][j] - mx[qq]); s_ += sc[qq][j]; }
    #pragma unroll
    for (int off = 32; off; off >>= 1) s_ += __shfl_xor(s_, off);
    if (lane == 0) red[qq][wv] = s_;
  }
  __syncthreads();
  #pragma unroll
  for (int qq = 0; qq < 8; qq++){
    float inv = 1.0f / (red[qq][0] + red[qq][1] + red[qq][2] + red[qq][3]);
    #pragma unroll
    for (int j = 0; j < 4; j++){
      int s = tid + j * 256;
      ATT[((size_t)hb * NL + l0 + qq) * NL + s] = sc[qq][j] * inv;
    }
  }
}

// ---------------------------------------------------------------------------
// K2b: CTX(B,L,H*64) = ATT(hb,L,L) @ VH(hb,L,64), concat in head order.
// Block: 128 q rows x 64 dv for one hb. KT=32.
// ---------------------------------------------------------------------------
__global__ __launch_bounds__(256) void k_pv(const float* __restrict__ ATT,
                                            const float* __restrict__ VH,
                                            float* __restrict__ CTX){
  __shared__ float Ps[32][128];
  __shared__ float Vs[32][64];
  const int hb = blockIdx.y;
  const int h = hb >> 2, b = hb & 3;
  const int q0 = blockIdx.x * 128;
  const int tid = threadIdx.x;
  const int ty = tid >> 4, tx = tid & 15;
  float acc[8][4];
  #pragma unroll
  for (int i = 0; i < 8; i++)
    #pragma unroll
    for (int j = 0; j < 4; j++) acc[i][j] = 0.f;

  for (int s0 = 0; s0 < NL; s0 += 32){
    #pragma unroll
    for (int li = 0; li < 2; li++){ // P tile: 128 rows x 32 s
      int idx = tid + li * 256;
      int r = idx >> 2, ch = idx & 3;
      const float* src = ATT + ((size_t)hb * NL + q0 + r) * NL + s0 + ch * 8;
      floatx4 v0 = *(const floatx4*)(src);
      floatx4 v1 = *(const floatx4*)(src + 4);
      #pragma unroll
      for (int e = 0; e < 4; e++){ Ps[ch*8 + e][r] = v0[e]; Ps[ch*8 + 4 + e][r] = v1[e]; }
    }
    { // V tile: 32 s x 64 dv
      int kk = tid >> 3, ch = tid & 7;
      const float* src = VH + ((size_t)hb * NL + s0 + kk) * NDK + ch * 8;
      floatx4 v0 = *(const floatx4*)(src);
      floatx4 v1 = *(const floatx4*)(src + 4);
      #pragma unroll
      for (int e = 0; e < 4; e++){ Vs[kk][ch*8 + e] = v0[e]; Vs[kk][ch*8 + 4 + e] = v1[e]; }
    }
    __syncthreads();
    #pragma unroll
    for (int kk = 0; kk < 32; kk++){
      float a[8], bq[4];
      #pragma unroll
      for (int i = 0; i < 8; i++) a[i] = Ps[kk][ty * 8 + i];
      #pragma unroll
      for (int j = 0; j < 4; j++) bq[j] = Vs[kk][tx * 4 + j];
      #pragma unroll
      for (int i = 0; i < 8; i++)
        #pragma unroll
        for (int j = 0; j < 4; j++) acc[i][j] += a[i] * bq[j];
    }
    __syncthreads();
  }
  #pragma unroll
  for (int i = 0; i < 8; i++){
    int l = q0 + ty * 8 + i;
    floatx4 o;
    #pragma unroll
    for (int j = 0; j < 4; j++) o[j] = acc[i][j];
    *(floatx4*)(CTX + ((size_t)b * NL + l) * ND + h * NDK + tx * 4) = o;
  }
}

// ---------------------------------------------------------------------------
// K3: X(B*L,1024) = CTX @ proj_w^T + proj_b + residual(q)  -> fp32, into d_out
// ---------------------------------------------------------------------------
__global__ __launch_bounds__(256) void k_projout(const float* __restrict__ CTX,
                                                 const float* __restrict__ PW,
                                                 const float* __restrict__ PB,
                                                 const float* __restrict__ RES,
                                                 float* __restrict__ X){
  __shared__ float As[16][128];
  __shared__ float Bs[16][128];
  const int tid = threadIdx.x;
  const int row0 = blockIdx.y * 128, col0 = blockIdx.x * 128;
  const int ty = tid >> 4, tx = tid & 15;
  float acc[8][8];
  #pragma unroll
  for (int i = 0; i < 8; i++)
    #pragma unroll
    for (int j = 0; j < 8; j++) acc[i][j] = 0.f;

  for (int k0 = 0; k0 < ND; k0 += 16){
    {
      int r = tid >> 1, ch = tid & 1;
      const float* src = CTX + (size_t)(row0 + r) * ND + k0 + ch * 8;
      floatx4 v0 = *(const floatx4*)(src);
      floatx4 v1 = *(const floatx4*)(src + 4);
      #pragma unroll
      for (int e = 0; e < 4; e++){ As[ch*8 + e][r] = v0[e]; As[ch*8 + 4 + e][r] = v1[e]; }
    }
    { // B[k][c] = PW[c*1024+k]
      int dl = tid >> 1, ch = tid & 1;
      const float* src = PW + (size_t)(col0 + dl) * ND + k0 + ch * 8;
      floatx4 v0 = *(const floatx4*)(src);
      floatx4 v1 = *(const floatx4*)(src + 4);
      #pragma unroll
      for (int e = 0; e < 4; e++){ Bs[ch*8 + e][dl] = v0[e]; Bs[ch*8 + 4 + e][dl] = v1[e]; }
    }
    __syncthreads();
    #pragma unroll
    for (int kk = 0; kk < 16; kk++){
      float a[8], bq[8];
      #pragma unroll
      for (int i = 0; i < 8; i++) a[i] = As[kk][ty * 8 + i];
      #pragma unroll
      for (int j = 0; j < 8; j++) bq[j] = Bs[kk][tx * 8 + j];
      #pragma unroll
      for (int i = 0; i < 8; i++)
        #pragma unroll
        for (int j = 0; j < 8; j++) acc[i][j] += a[i] * bq[j];
    }
    __syncthreads();
  }
  #pragma unroll
  for (int i = 0; i < 8; i++){
    int r = row0 + ty * 8 + i;
    #pragma unroll
    for (int j = 0; j < 8; j++){
      int c = col0 + tx * 8 + j;
      X[(size_t)r * ND + c] = acc[i][j] + PB[c] + RES[(size_t)r * ND + c];
    }
  }
}

// ---------------------------------------------------------------------------
// K4: per-channel mean + rstd over B*L rows.  MV[d]=mean, MV[1024+d]=rstd
// ---------------------------------------------------------------------------
__global__ __launch_bounds__(256) void k_bnstats(const float* __restrict__ X,
                                                 float* __restrict__ MV){
  const int d = blockIdx.x, tid = threadIdx.x;
  float s = 0.f, s2 = 0.f;
  for (int r = tid; r < NB * NL; r += 256){
    float v = X[(size_t)r * ND + d];
    s += v; s2 += v * v;
  }
  #pragma unroll
  for (int off = 32; off; off >>= 1){ s += __shfl_xor(s, off); s2 += __shfl_xor(s2, off); }
  __shared__ float rs[8];
  const int wv = tid >> 6, lane = tid & 63;
  if (lane == 0){ rs[wv] = s; rs[4 + wv] = s2; }
  __syncthreads();
  if (tid == 0){
    float S = rs[0] + rs[1] + rs[2] + rs[3];
    float S2 = rs[4] + rs[5] + rs[6] + rs[7];
    float mean = S * (1.0f / (NB * NL));
    float var = S2 * (1.0f / (NB * NL)) - mean * mean;
    MV[d] = mean;
    MV[ND + d] = rsqrtf(var + 1e-5f);
  }
}

// ---------------------------------------------------------------------------
// K5: normalize + affine IN PLACE on the fp32 x-region of d_out
// ---------------------------------------------------------------------------
__global__ __launch_bounds__(256) void k_bnapply(float* __restrict__ X,
                                                 const float* __restrict__ MV,
                                                 const float* __restrict__ G,
                                                 const float* __restrict__ Bt){
  const int idx = blockIdx.x * 256 + threadIdx.x;
  const size_t base = (size_t)idx * 8;
  const int d0 = (int)(base & (ND - 1));
  floatx4 x0 = *(const floatx4*)(X + base);
  floatx4 x1 = *(const floatx4*)(X + base + 4);
  floatx4 o0, o1;
  #pragma unroll
  for (int e = 0; e < 4; e++){
    int d = d0 + e;
    o0[e] = (x0[e] - MV[d]) * MV[ND + d] * G[d] + Bt[d];
    int d2 = d0 + 4 + e;
    o1[e] = (x1[e] - MV[d2]) * MV[ND + d2] * G[d2] + Bt[d2];
  }
  *(floatx4*)(X + base) = o0;
  *(floatx4*)(X + base + 4) = o1;
}

// ---------------------------------------------------------------------------
extern "C" void kernel_launch(void* const* d_in, const int* in_sizes, int n_in,
                              void* d_out, int out_size, void* d_ws, size_t ws_size,
                              hipStream_t stream){
  const float* q      = (const float*)d_in[0];
  const float* k      = (const float*)d_in[1];
  const float* v      = (const float*)d_in[2];
  const int*   mask   = (const int*)d_in[3];
  const float* w_qs   = (const float*)d_in[4];
  const float* w_ks   = (const float*)d_in[5];
  const float* w_vs   = (const float*)d_in[6];
  const float* proj_w = (const float*)d_in[7];
  const float* proj_b = (const float*)d_in[8];
  const float* gamma  = (const float*)d_in[9];
  const float* beta   = (const float*)d_in[10];

  float* out_x   = (float*)d_out;
  float* out_att = out_x + (size_t)NB * NL * ND;   // attns at elem offset 4,194,304

  char* ws = (char*)d_ws;
  float* qh  = (float*)(ws);                 // 16 MB
  float* kh  = (float*)(ws + (16u << 20));   // 16 MB
  float* vh  = (float*)(ws + (32u << 20));   // 16 MB
  float* ctx = (float*)(ws);                 // reuses qh (dead after k_scores)
  float* MV  = (float*)(ws + (48u << 20));   // 8 KB

  dim3 blk(256);
  k_proj<<<dim3(8, 32), blk, 0, stream>>>(q, w_qs, qh);
  k_proj<<<dim3(8, 32), blk, 0, stream>>>(k, w_ks, kh);
  k_proj<<<dim3(8, 32), blk, 0, stream>>>(v, w_vs, vh);
  k_scores<<<dim3(NH * NB * (NL / 8)), blk, 0, stream>>>(qh, kh, mask, out_att);
  k_pv<<<dim3(8, NH * NB), blk, 0, stream>>>(out_att, vh, ctx);
  k_projout<<<dim3(8, 32), blk, 0, stream>>>(ctx, proj_w, proj_b, q, out_x);
  k_bnstats<<<dim3(ND), blk, 0, stream>>>(out_x, MV);
  k_bnapply<<<dim3(NB * NL * ND / 8 / 256), blk, 0, stream>>>(out_x, MV, gamma, beta);
}

// Round 4
// 449.094 us; speedup vs baseline: 5.5702x; 5.5702x over previous
//
#include <hip/hip_runtime.h>

typedef unsigned short ushort;
typedef __attribute__((ext_vector_type(4))) float floatx4;
typedef __bf16 bf16x8 __attribute__((ext_vector_type(8)));
typedef float f32x4 __attribute__((ext_vector_type(4)));

constexpr int NB = 4;     // batch
constexpr int NL = 1024;  // seq len
constexpr int ND = 1024;  // d_model
constexpr int NH = 16;    // heads
constexpr int NDK = 64;   // d_k = d_v

__device__ __forceinline__ float b2f(ushort u){
  union { unsigned int i; float f; } x; x.i = ((unsigned int)u) << 16; return x.f;
}
__device__ __forceinline__ ushort f2b(float f){
  union { float f; unsigned int i; } x; x.f = f;
  unsigned int u = x.i;
  u += 0x7fffu + ((u >> 16) & 1u);   // RNE
  return (ushort)(u >> 16);
}

union P8 { bf16x8 b; ushort u[8]; };

#define MFMA(a,b,c) __builtin_amdgcn_mfma_f32_16x16x32_bf16((a),(b),(c),0,0,0)

// ---------------------------------------------------------------------------
// K0: pack mask int32 -> bits.  One thread per mask element; 64-lane ballot
// packs one u64 word.  Grid MUST be NB*NL*NL/256 blocks.
// ---------------------------------------------------------------------------
__global__ __launch_bounds__(256) void k_maskpack(const int* __restrict__ M,
                                                  unsigned long long* __restrict__ MB){
  const int gid = blockIdx.x * 256 + threadIdx.x;
  const int widx = gid >> 6;
  const int l = gid & 63;
  int m = M[(size_t)widx * 64 + l];
  unsigned long long bal = __ballot(m != 0);
  if (l == 0) MB[widx] = bal;
}

// ---------------------------------------------------------------------------
// K1: MFMA projection.  OUT(H*B, L, 64) bf16 = X(4096,1024) @ W(H,1024,64)
// 128x128 tile, BK=64, 4 waves (2x2), per-wave 4x4 subtiles.
// ---------------------------------------------------------------------------
__global__ __launch_bounds__(256) void k_projm(const float* __restrict__ X,
                                               const float* __restrict__ W,
                                               ushort* __restrict__ OUT){
  __shared__ bf16x8 Ach[8 * 128];
  __shared__ bf16x8 Bch[8 * 128];
  const int tid = threadIdx.x;
  const int lane = tid & 63, wid = tid >> 6;
  const int g = lane >> 4, c = lane & 15;
  const int row0 = blockIdx.y * 128, col0 = blockIdx.x * 128;
  const int wm = (wid >> 1) * 64, wn = (wid & 1) * 64;

  f32x4 zero = {0.f, 0.f, 0.f, 0.f};
  f32x4 acc[4][4];
  #pragma unroll
  for (int i = 0; i < 4; i++)
    #pragma unroll
    for (int j = 0; j < 4; j++) acc[i][j] = zero;

  for (int k0 = 0; k0 < ND; k0 += 64){
    // stage A (fp32 -> bf16), entries [kc][m]
    #pragma unroll
    for (int i = 0; i < 4; i++){
      int e = tid + i * 256;
      int kc = e & 7, m = e >> 3;
      const float* src = X + (size_t)(row0 + m) * ND + k0 + kc * 8;
      floatx4 v0 = *(const floatx4*)src;
      floatx4 v1 = *(const floatx4*)(src + 4);
      P8 p;
      #pragma unroll
      for (int j = 0; j < 4; j++){ p.u[j] = f2b(v0[j]); p.u[4 + j] = f2b(v1[j]); }
      Ach[kc * 128 + m] = p.b;
    }
    // stage B: entry [kc][n] holds W[h][k0+kc*8 .. +8][dk], strided-gather
    {
      int n = tid & 127;
      int hh = (col0 + n) >> 6, dk = (col0 + n) & 63;
      #pragma unroll
      for (int i = 0; i < 4; i++){
        int kc = i * 2 + (tid >> 7);
        P8 p;
        #pragma unroll
        for (int j = 0; j < 8; j++)
          p.u[j] = f2b(W[((size_t)hh * ND + k0 + kc * 8 + j) * NDK + dk]);
        Bch[kc * 128 + n] = p.b;
      }
    }
    __syncthreads();
    bf16x8 bfr[4][2];
    #pragma unroll
    for (int ni = 0; ni < 4; ni++){
      bfr[ni][0] = Bch[(0 + g) * 128 + wn + ni * 16 + c];
      bfr[ni][1] = Bch[(4 + g) * 128 + wn + ni * 16 + c];
    }
    #pragma unroll
    for (int mi = 0; mi < 4; mi++){
      bf16x8 a0 = Ach[(0 + g) * 128 + wm + mi * 16 + c];
      bf16x8 a1 = Ach[(4 + g) * 128 + wm + mi * 16 + c];
      #pragma unroll
      for (int ni = 0; ni < 4; ni++){
        acc[mi][ni] = MFMA(a0, bfr[ni][0], acc[mi][ni]);
        acc[mi][ni] = MFMA(a1, bfr[ni][1], acc[mi][ni]);
      }
    }
    __syncthreads();
  }
  // epilogue: bf16 OUT[(h*NB+b)][l][dk]
  #pragma unroll
  for (int mi = 0; mi < 4; mi++){
    #pragma unroll
    for (int ni = 0; ni < 4; ni++){
      #pragma unroll
      for (int r = 0; r < 4; r++){
        int m = row0 + wm + mi * 16 + g * 4 + r;
        int n = col0 + wn + ni * 16 + c;
        int bb = m >> 10, ls = m & 1023;
        int hh = n >> 6, dk = n & 63;
        OUT[(((size_t)hh * NB + bb) * NL + ls) * NDK + dk] = f2b(acc[mi][ni][r]);
      }
    }
  }
}

// ---------------------------------------------------------------------------
// K2: scores + exp (no max-sub).  ATTU fp32 = exp(QK^T/32) (0 where masked),
// DEN[hb][q] = row sums.  Block: 64 q-rows x one hb; 4 waves x 16 q.
// ---------------------------------------------------------------------------
__global__ __launch_bounds__(256) void k_scoresm(const ushort* __restrict__ QH,
                                                 const ushort* __restrict__ KH,
                                                 const unsigned* __restrict__ MB,
                                                 float* __restrict__ ATTU,
                                                 float* __restrict__ DEN){
  __shared__ bf16x8 Qch[8 * 64];
  __shared__ bf16x8 Kch[8 * 128];
  const int tid = threadIdx.x;
  const int lane = tid & 63, wid = tid >> 6;
  const int g = lane >> 4, c = lane & 15;
  const int q0 = blockIdx.x * 64;
  const int hb = blockIdx.y;
  const int b = hb & 3;

  // stage Q once: entries [kc][qr]
  #pragma unroll
  for (int i = 0; i < 2; i++){
    int e = tid + i * 256;
    int kc = e & 7, qr = e >> 3;
    Qch[kc * 64 + qr] = *(const bf16x8*)(QH + ((size_t)hb * NL + q0 + qr) * NDK + kc * 8);
  }
  __syncthreads();
  bf16x8 qf0 = Qch[(0 + g) * 64 + wid * 16 + c];
  bf16x8 qf1 = Qch[(4 + g) * 64 + wid * 16 + c];

  float rs[4] = {0.f, 0.f, 0.f, 0.f};
  const int qrow = q0 + wid * 16 + g * 4;   // + r

  for (int s0 = 0; s0 < NL; s0 += 128){
    __syncthreads();
    #pragma unroll
    for (int i = 0; i < 4; i++){
      int e = tid + i * 256;
      int kc = e & 7, sr = e >> 3;
      Kch[kc * 128 + sr] = *(const bf16x8*)(KH + ((size_t)hb * NL + s0 + sr) * NDK + kc * 8);
    }
    __syncthreads();
    #pragma unroll
    for (int sub = 0; sub < 8; sub++){
      bf16x8 kf0 = Kch[(0 + g) * 128 + sub * 16 + c];
      bf16x8 kf1 = Kch[(4 + g) * 128 + sub * 16 + c];
      f32x4 a = {0.f, 0.f, 0.f, 0.f};
      a = MFMA(qf0, kf0, a);
      a = MFMA(qf1, kf1, a);
      int s = s0 + sub * 16 + c;
      #pragma unroll
      for (int r = 0; r < 4; r++){
        int q = qrow + r;
        unsigned w = MB[((unsigned)(b << 10) + q) * 32 + (s0 >> 5) + (sub >> 1)];
        bool masked = (w >> ((sub & 1) * 16 + c)) & 1u;
        float p = masked ? 0.f : __expf(a[r] * (1.f / 32.f));
        rs[r] += p;
        ATTU[((size_t)hb * NL + q) * NL + s] = p;
      }
    }
  }
  // reduce row sums across the 16 lanes of each row group
  #pragma unroll
  for (int off = 1; off < 16; off <<= 1){
    #pragma unroll
    for (int r = 0; r < 4; r++) rs[r] += __shfl_xor(rs[r], off);
  }
  if (c == 0){
    #pragma unroll
    for (int r = 0; r < 4; r++) DEN[(size_t)hb * NL + qrow + r] = rs[r];
  }
}

// ---------------------------------------------------------------------------
// K3: PV.  Normalizes ATTU in place (fp32 attns output) while staging P bf16;
// CTX(B,L,1024) bf16 = attn @ V.  Block: 128 q x 64 dv x one hb.
// ---------------------------------------------------------------------------
__global__ __launch_bounds__(256) void k_pvm(float* __restrict__ ATTU,
                                             const ushort* __restrict__ VH,
                                             const float* __restrict__ DEN,
                                             ushort* __restrict__ CTX){
  __shared__ bf16x8 Pch[8 * 128];
  __shared__ bf16x8 Vch[8 * 64];
  const int tid = threadIdx.x;
  const int lane = tid & 63, wid = tid >> 6;
  const int g = lane >> 4, c = lane & 15;
  const int q0 = blockIdx.x * 128;
  const int hb = blockIdx.y;
  const int h = hb >> 2, b = hb & 3;

  float invd[4];
  #pragma unroll
  for (int i = 0; i < 4; i++)
    invd[i] = 1.f / DEN[(size_t)hb * NL + q0 + (tid >> 3) + 32 * i];

  f32x4 zero = {0.f, 0.f, 0.f, 0.f};
  f32x4 acc[2][4];
  #pragma unroll
  for (int i = 0; i < 2; i++)
    #pragma unroll
    for (int j = 0; j < 4; j++) acc[i][j] = zero;
  const int wm = wid * 32;

  for (int s0 = 0; s0 < NL; s0 += 64){
    __syncthreads();
    // stage P (normalize + write back fp32, keep bf16 for MFMA)
    #pragma unroll
    for (int i = 0; i < 4; i++){
      int e = tid + i * 256;
      int kc = e & 7, qr = e >> 3;
      float* src = ATTU + ((size_t)hb * NL + q0 + qr) * NL + s0 + kc * 8;
      floatx4 v0 = *(floatx4*)src;
      floatx4 v1 = *(floatx4*)(src + 4);
      P8 p;
      #pragma unroll
      for (int j = 0; j < 4; j++){
        float n0 = v0[j] * invd[i], n1 = v1[j] * invd[i];
        v0[j] = n0; v1[j] = n1;
        p.u[j] = f2b(n0); p.u[4 + j] = f2b(n1);
      }
      *(floatx4*)src = v0;
      *(floatx4*)(src + 4) = v1;
      Pch[kc * 128 + qr] = p.b;
    }
    // stage V: entry [kc][dv] = VH[s0+kc*8 .. +8][dv]
    {
      int dv = lane;
      #pragma unroll
      for (int rep = 0; rep < 2; rep++){
        int kc = wid + rep * 4;
        P8 p;
        #pragma unroll
        for (int j = 0; j < 8; j++)
          p.u[j] = VH[((size_t)hb * NL + s0 + kc * 8 + j) * NDK + dv];
        Vch[kc * 64 + dv] = p.b;
      }
    }
    __syncthreads();
    bf16x8 vf[4][2];
    #pragma unroll
    for (int ni = 0; ni < 4; ni++){
      vf[ni][0] = Vch[(0 + g) * 64 + ni * 16 + c];
      vf[ni][1] = Vch[(4 + g) * 64 + ni * 16 + c];
    }
    #pragma unroll
    for (int mi = 0; mi < 2; mi++){
      bf16x8 pf0 = Pch[(0 + g) * 128 + wm + mi * 16 + c];
      bf16x8 pf1 = Pch[(4 + g) * 128 + wm + mi * 16 + c];
      #pragma unroll
      for (int ni = 0; ni < 4; ni++){
        acc[mi][ni] = MFMA(pf0, vf[ni][0], acc[mi][ni]);
        acc[mi][ni] = MFMA(pf1, vf[ni][1], acc[mi][ni]);
      }
    }
  }
  #pragma unroll
  for (int mi = 0; mi < 2; mi++)
    #pragma unroll
    for (int ni = 0; ni < 4; ni++)
      #pragma unroll
      for (int r = 0; r < 4; r++){
        int q = q0 + wm + mi * 16 + g * 4 + r;
        int dv = ni * 16 + c;
        CTX[((size_t)b * NL + q) * ND + h * NDK + dv] = f2b(acc[mi][ni][r]);
      }
}

// ---------------------------------------------------------------------------
// K4: output projection + bias + residual.  X fp32 = CTX@PW^T + PB + RES
// ---------------------------------------------------------------------------
__global__ __launch_bounds__(256) void k_projo(const ushort* __restrict__ CTX,
                                               const float* __restrict__ PW,
                                               const float* __restrict__ PB,
                                               const float* __restrict__ RES,
                                               float* __restrict__ X){
  __shared__ bf16x8 Ach[8 * 128];
  __shared__ bf16x8 Bch[8 * 128];
  const int tid = threadIdx.x;
  const int lane = tid & 63, wid = tid >> 6;
  const int g = lane >> 4, c = lane & 15;
  const int row0 = blockIdx.y * 128, col0 = blockIdx.x * 128;
  const int wm = (wid >> 1) * 64, wn = (wid & 1) * 64;

  f32x4 zero = {0.f, 0.f, 0.f, 0.f};
  f32x4 acc[4][4];
  #pragma unroll
  for (int i = 0; i < 4; i++)
    #pragma unroll
    for (int j = 0; j < 4; j++) acc[i][j] = zero;

  for (int k0 = 0; k0 < ND; k0 += 64){
    #pragma unroll
    for (int i = 0; i < 4; i++){
      int e = tid + i * 256;
      int kc = e & 7, m = e >> 3;
      Ach[kc * 128 + m] = *(const bf16x8*)(CTX + (size_t)(row0 + m) * ND + k0 + kc * 8);
    }
    #pragma unroll
    for (int i = 0; i < 4; i++){
      int e = tid + i * 256;
      int kc = e & 7, n = e >> 3;
      const float* src = PW + (size_t)(col0 + n) * ND + k0 + kc * 8;
      floatx4 v0 = *(const floatx4*)src;
      floatx4 v1 = *(const floatx4*)(src + 4);
      P8 p;
      #pragma unroll
      for (int j = 0; j < 4; j++){ p.u[j] = f2b(v0[j]); p.u[4 + j] = f2b(v1[j]); }
      Bch[kc * 128 + n] = p.b;
    }
    __syncthreads();
    bf16x8 bfr[4][2];
    #pragma unroll
    for (int ni = 0; ni < 4; ni++){
      bfr[ni][0] = Bch[(0 + g) * 128 + wn + ni * 16 + c];
      bfr[ni][1] = Bch[(4 + g) * 128 + wn + ni * 16 + c];
    }
    #pragma unroll
    for (int mi = 0; mi < 4; mi++){
      bf16x8 a0 = Ach[(0 + g) * 128 + wm + mi * 16 + c];
      bf16x8 a1 = Ach[(4 + g) * 128 + wm + mi * 16 + c];
      #pragma unroll
      for (int ni = 0; ni < 4; ni++){
        acc[mi][ni] = MFMA(a0, bfr[ni][0], acc[mi][ni]);
        acc[mi][ni] = MFMA(a1, bfr[ni][1], acc[mi][ni]);
      }
    }
    __syncthreads();
  }
  #pragma unroll
  for (int mi = 0; mi < 4; mi++)
    #pragma unroll
    for (int ni = 0; ni < 4; ni++)
      #pragma unroll
      for (int r = 0; r < 4; r++){
        int m = row0 + wm + mi * 16 + g * 4 + r;
        int n = col0 + wn + ni * 16 + c;
        X[(size_t)m * ND + n] = acc[mi][ni][r] + PB[n] + RES[(size_t)m * ND + n];
      }
}

// ---------------------------------------------------------------------------
// K5a/K5b: BatchNorm stats (coalesced two-stage), K5c: apply in place
// ---------------------------------------------------------------------------
__global__ __launch_bounds__(256) void k_bnst1(const float* __restrict__ X,
                                               float* __restrict__ part){
  const int cx = blockIdx.x * 256 + threadIdx.x;
  const int r0 = blockIdx.y * 256;
  float s = 0.f, s2 = 0.f;
  for (int r = 0; r < 256; r++){
    float v = X[(size_t)(r0 + r) * ND + cx];
    s += v; s2 += v * v;
  }
  part[(size_t)(blockIdx.y * 2 + 0) * ND + cx] = s;
  part[(size_t)(blockIdx.y * 2 + 1) * ND + cx] = s2;
}

__global__ __launch_bounds__(256) void k_bnst2(const float* __restrict__ part,
                                               float* __restrict__ MV){
  const int cx = blockIdx.x * 256 + threadIdx.x;
  float s = 0.f, s2 = 0.f;
  #pragma unroll
  for (int i = 0; i < 16; i++){
    s  += part[(size_t)(i * 2 + 0) * ND + cx];
    s2 += part[(size_t)(i * 2 + 1) * ND + cx];
  }
  float mean = s * (1.f / (NB * NL));
  float var = s2 * (1.f / (NB * NL)) - mean * mean;
  MV[cx] = mean;
  MV[ND + cx] = rsqrtf(var + 1e-5f);
}

__global__ __launch_bounds__(256) void k_bnapply(float* __restrict__ X,
                                                 const float* __restrict__ MV,
                                                 const float* __restrict__ G,
                                                 const float* __restrict__ Bt){
  const int idx = blockIdx.x * 256 + threadIdx.x;
  const size_t base = (size_t)idx * 8;
  const int d0 = (int)(base & (ND - 1));
  floatx4 x0 = *(const floatx4*)(X + base);
  floatx4 x1 = *(const floatx4*)(X + base + 4);
  floatx4 o0, o1;
  #pragma unroll
  for (int e = 0; e < 4; e++){
    int d = d0 + e;
    o0[e] = (x0[e] - MV[d]) * MV[ND + d] * G[d] + Bt[d];
    int d2 = d0 + 4 + e;
    o1[e] = (x1[e] - MV[d2]) * MV[ND + d2] * G[d2] + Bt[d2];
  }
  *(floatx4*)(X + base) = o0;
  *(floatx4*)(X + base + 4) = o1;
}

// ---------------------------------------------------------------------------
extern "C" void kernel_launch(void* const* d_in, const int* in_sizes, int n_in,
                              void* d_out, int out_size, void* d_ws, size_t ws_size,
                              hipStream_t stream){
  const float* q      = (const float*)d_in[0];
  const float* k      = (const float*)d_in[1];
  const float* v      = (const float*)d_in[2];
  const int*   mask   = (const int*)d_in[3];
  const float* w_qs   = (const float*)d_in[4];
  const float* w_ks   = (const float*)d_in[5];
  const float* w_vs   = (const float*)d_in[6];
  const float* proj_w = (const float*)d_in[7];
  const float* proj_b = (const float*)d_in[8];
  const float* gamma  = (const float*)d_in[9];
  const float* beta   = (const float*)d_in[10];

  float* out_x   = (float*)d_out;
  float* out_att = out_x + (size_t)NB * NL * ND;

  char* ws = (char*)d_ws;
  ushort* qh  = (ushort*)(ws);                       // 8 MB
  ushort* kh  = (ushort*)(ws + (8u  << 20));         // 8 MB
  ushort* vh  = (ushort*)(ws + (16u << 20));         // 8 MB
  ushort* ctx = (ushort*)(ws + (24u << 20));         // 8 MB
  float*  den = (float*) (ws + (32u << 20));         // 256 KB
  unsigned long long* mb = (unsigned long long*)(ws + (33u << 20));  // 512 KB
  float*  part = (float*)(ws + (34u << 20));         // 128 KB
  float*  mv   = (float*)(ws + (35u << 20));         // 8 KB

  dim3 blk(256);
  k_maskpack<<<dim3(NB * NL * NL / 256), blk, 0, stream>>>(mask, mb);
  k_projm<<<dim3(8, 32), blk, 0, stream>>>(q, w_qs, qh);
  k_projm<<<dim3(8, 32), blk, 0, stream>>>(k, w_ks, kh);
  k_projm<<<dim3(8, 32), blk, 0, stream>>>(v, w_vs, vh);
  k_scoresm<<<dim3(16, NH * NB), blk, 0, stream>>>(qh, kh, (const unsigned*)mb, out_att, den);
  k_pvm<<<dim3(8, NH * NB), blk, 0, stream>>>(out_att, vh, den, ctx);
  k_projo<<<dim3(8, 32), blk, 0, stream>>>(ctx, proj_w, proj_b, q, out_x);
  k_bnst1<<<dim3(4, 16), blk, 0, stream>>>(out_x, part);
  k_bnst2<<<dim3(4), blk, 0, stream>>>(part, mv);
  k_bnapply<<<dim3(NB * NL * ND / 8 / 256), blk, 0, stream>>>(out_x, mv, gamma, beta);
}

// Round 5
// 411.677 us; speedup vs baseline: 6.0765x; 1.0909x over previous
//
#include <hip/hip_runtime.h>

typedef unsigned short ushort;
typedef __attribute__((ext_vector_type(4))) float floatx4;
typedef __bf16 bf16x8 __attribute__((ext_vector_type(8)));
typedef float f32x4 __attribute__((ext_vector_type(4)));

constexpr int NB = 4;     // batch
constexpr int NL = 1024;  // seq len
constexpr int ND = 1024;  // d_model
constexpr int NH = 16;    // heads
constexpr int NDK = 64;   // d_k = d_v

__device__ __forceinline__ float b2f(ushort u){
  union { unsigned int i; float f; } x; x.i = ((unsigned int)u) << 16; return x.f;
}
__device__ __forceinline__ ushort f2b(float f){
  union { float f; unsigned int i; } x; x.f = f;
  unsigned int u = x.i;
  u += 0x7fffu + ((u >> 16) & 1u);   // RNE
  return (ushort)(u >> 16);
}

union P8 { bf16x8 b; ushort u[8]; };

#define MFMA(a,b,c) __builtin_amdgcn_mfma_f32_16x16x32_bf16((a),(b),(c),0,0,0)

// ---------------------------------------------------------------------------
// K0: pack mask int32 -> bits.  One thread per mask element; 64-lane ballot.
// ---------------------------------------------------------------------------
__global__ __launch_bounds__(256) void k_maskpack(const int* __restrict__ M,
                                                  unsigned long long* __restrict__ MB){
  const int gid = blockIdx.x * 256 + threadIdx.x;
  const int widx = gid >> 6;
  const int l = gid & 63;
  int m = M[(size_t)widx * 64 + l];
  unsigned long long bal = __ballot(m != 0);
  if (l == 0) MB[widx] = bal;
}

// ---------------------------------------------------------------------------
// K1: MFMA projection.  OUT(H*B, L, 64) bf16 = X(4096,1024) @ W(H,1024,64)
// ---------------------------------------------------------------------------
__global__ __launch_bounds__(256) void k_projm(const float* __restrict__ X,
                                               const float* __restrict__ W,
                                               ushort* __restrict__ OUT){
  __shared__ bf16x8 Ach[8 * 128];
  __shared__ bf16x8 Bch[8 * 128];
  const int tid = threadIdx.x;
  const int lane = tid & 63, wid = tid >> 6;
  const int g = lane >> 4, c = lane & 15;
  const int row0 = blockIdx.y * 128, col0 = blockIdx.x * 128;
  const int wm = (wid >> 1) * 64, wn = (wid & 1) * 64;

  f32x4 zero = {0.f, 0.f, 0.f, 0.f};
  f32x4 acc[4][4];
  #pragma unroll
  for (int i = 0; i < 4; i++)
    #pragma unroll
    for (int j = 0; j < 4; j++) acc[i][j] = zero;

  for (int k0 = 0; k0 < ND; k0 += 64){
    #pragma unroll
    for (int i = 0; i < 4; i++){
      int e = tid + i * 256;
      int kc = e & 7, m = e >> 3;
      const float* src = X + (size_t)(row0 + m) * ND + k0 + kc * 8;
      floatx4 v0 = *(const floatx4*)src;
      floatx4 v1 = *(const floatx4*)(src + 4);
      P8 p;
      #pragma unroll
      for (int j = 0; j < 4; j++){ p.u[j] = f2b(v0[j]); p.u[4 + j] = f2b(v1[j]); }
      Ach[kc * 128 + m] = p.b;
    }
    {
      int n = tid & 127;
      int hh = (col0 + n) >> 6, dk = (col0 + n) & 63;
      #pragma unroll
      for (int i = 0; i < 4; i++){
        int kc = i * 2 + (tid >> 7);
        P8 p;
        #pragma unroll
        for (int j = 0; j < 8; j++)
          p.u[j] = f2b(W[((size_t)hh * ND + k0 + kc * 8 + j) * NDK + dk]);
        Bch[kc * 128 + n] = p.b;
      }
    }
    __syncthreads();
    bf16x8 bfr[4][2];
    #pragma unroll
    for (int ni = 0; ni < 4; ni++){
      bfr[ni][0] = Bch[(0 + g) * 128 + wn + ni * 16 + c];
      bfr[ni][1] = Bch[(4 + g) * 128 + wn + ni * 16 + c];
    }
    #pragma unroll
    for (int mi = 0; mi < 4; mi++){
      bf16x8 a0 = Ach[(0 + g) * 128 + wm + mi * 16 + c];
      bf16x8 a1 = Ach[(4 + g) * 128 + wm + mi * 16 + c];
      #pragma unroll
      for (int ni = 0; ni < 4; ni++){
        acc[mi][ni] = MFMA(a0, bfr[ni][0], acc[mi][ni]);
        acc[mi][ni] = MFMA(a1, bfr[ni][1], acc[mi][ni]);
      }
    }
    __syncthreads();
  }
  #pragma unroll
  for (int mi = 0; mi < 4; mi++){
    #pragma unroll
    for (int ni = 0; ni < 4; ni++){
      #pragma unroll
      for (int r = 0; r < 4; r++){
        int m = row0 + wm + mi * 16 + g * 4 + r;
        int n = col0 + wn + ni * 16 + c;
        int bb = m >> 10, ls = m & 1023;
        int hh = n >> 6, dk = n & 63;
        OUT[(((size_t)hh * NB + bb) * NL + ls) * NDK + dk] = f2b(acc[mi][ni][r]);
      }
    }
  }
}

// ---------------------------------------------------------------------------
// K2: fused attention.  Swapped QK^T (D = K·Q^T = scores^T) so each lane owns
// 4 consecutive s for one q.  Pass 1: row denominators (no barriers, K/Q frags
// direct from global).  Pass 2: normalized p -> fp32 attns (coalesced 16B) +
// bf16 p -> per-wave LDS -> PV MFMA.  Block = 64 q-rows, one hb; 4 waves.
// ---------------------------------------------------------------------------
__global__ __launch_bounds__(256) void k_attn(const ushort* __restrict__ QH,
                                              const ushort* __restrict__ KH,
                                              const ushort* __restrict__ VH,
                                              const unsigned* __restrict__ MB,
                                              float* __restrict__ ATT,
                                              ushort* __restrict__ CTX){
  __shared__ bf16x8 Vch[8 * 64];        // [kc][dv] for a 64-s tile
  __shared__ ushort Ps[4][16][72];      // per-wave P: [q_local][s_local(+pad)]
  const int tid = threadIdx.x;
  const int lane = tid & 63, wid = tid >> 6;
  const int g = lane >> 4, c = lane & 15;
  const int q0 = blockIdx.x * 64;
  const int hb = blockIdx.y;
  const int h = hb >> 2, b = hb & 3;

  const int q = q0 + wid * 16 + c;      // this lane's q row (both passes)
  const size_t qkbase = (size_t)hb * NL;

  // Q fragments: B-operand (lane: n=c -> q, k=g*8+e -> dk)
  bf16x8 qf0 = *(const bf16x8*)(QH + (qkbase + q) * NDK + g * 8);
  bf16x8 qf1 = *(const bf16x8*)(QH + (qkbase + q) * NDK + 32 + g * 8);

  const unsigned mrow = ((unsigned)(b << 10) + q) * 32;   // mask word base
  const int mshift_g = g * 4;

  // ---- pass 1: denominators ----
  float rs = 0.f;
  for (int sub = 0; sub < 64; ++sub){
    const ushort* kr = KH + (qkbase + sub * 16 + c) * NDK;
    bf16x8 kf0 = *(const bf16x8*)(kr + g * 8);
    bf16x8 kf1 = *(const bf16x8*)(kr + 32 + g * 8);
    f32x4 a = {0.f, 0.f, 0.f, 0.f};
    a = MFMA(kf0, qf0, a);
    a = MFMA(kf1, qf1, a);
    unsigned w = MB[mrow + (sub >> 1)];
    unsigned bits4 = (w >> (((sub & 1) << 4) + mshift_g)) & 0xFu;
    #pragma unroll
    for (int r = 0; r < 4; r++)
      rs += ((bits4 >> r) & 1u) ? 0.f : __expf(a[r] * (1.f / 32.f));
  }
  rs += __shfl_xor(rs, 16);
  rs += __shfl_xor(rs, 32);
  const float invd = 1.f / rs;

  // ---- pass 2: write attns + PV ----
  f32x4 zero = {0.f, 0.f, 0.f, 0.f};
  f32x4 acc[4];
  #pragma unroll
  for (int i = 0; i < 4; i++) acc[i] = zero;

  for (int t = 0; t < 16; ++t){
    __syncthreads();
    // stage V tile: entry [kc][dv] = VH[t*64 + kc*8 .. +8][dv]
    #pragma unroll
    for (int i = 0; i < 2; i++){
      int idx = tid * 2 + i;
      int kc = idx >> 6, dv = idx & 63;
      P8 p;
      #pragma unroll
      for (int j = 0; j < 8; j++)
        p.u[j] = VH[(qkbase + t * 64 + kc * 8 + j) * NDK + dv];
      Vch[kc * 64 + dv] = p.b;
    }
    __syncthreads();

    #pragma unroll
    for (int sub2 = 0; sub2 < 4; ++sub2){
      int sub = t * 4 + sub2;
      const ushort* kr = KH + (qkbase + sub * 16 + c) * NDK;
      bf16x8 kf0 = *(const bf16x8*)(kr + g * 8);
      bf16x8 kf1 = *(const bf16x8*)(kr + 32 + g * 8);
      f32x4 a = {0.f, 0.f, 0.f, 0.f};
      a = MFMA(kf0, qf0, a);
      a = MFMA(kf1, qf1, a);
      unsigned w = MB[mrow + (sub >> 1)];
      unsigned bits4 = (w >> (((sub & 1) << 4) + mshift_g)) & 0xFu;
      floatx4 pn;
      union { unsigned long long ll; ushort u[4]; } pw;
      #pragma unroll
      for (int r = 0; r < 4; r++){
        float p = ((bits4 >> r) & 1u) ? 0.f : __expf(a[r] * (1.f / 32.f)) * invd;
        pn[r] = p;
        pw.u[r] = f2b(p);
      }
      // coalesced fp32 attns write: 4 consecutive s at fixed q
      *(floatx4*)(ATT + ((size_t)hb * NL + q) * NL + sub * 16 + g * 4) = pn;
      // bf16 P into per-wave LDS (row = q_local = c)
      *(unsigned long long*)&Ps[wid][c][sub2 * 16 + g * 4] = pw.ll;
    }

    // PV: A = P (row=c -> q_local, k = s), B = V
    #pragma unroll
    for (int ss = 0; ss < 2; ++ss){
      bf16x8 afr = *(bf16x8*)&Ps[wid][c][ss * 32 + g * 8];
      #pragma unroll
      for (int ni = 0; ni < 4; ni++){
        bf16x8 vfr = Vch[(ss * 4 + g) * 64 + ni * 16 + c];
        acc[ni] = MFMA(afr, vfr, acc[ni]);
      }
    }
  }

  // epilogue: ctx[q][h*64+dv]
  #pragma unroll
  for (int ni = 0; ni < 4; ni++)
    #pragma unroll
    for (int r = 0; r < 4; r++){
      int qq = q0 + wid * 16 + g * 4 + r;
      int dv = ni * 16 + c;
      CTX[((size_t)b * NL + qq) * ND + h * NDK + dv] = f2b(acc[ni][r]);
    }
}

// ---------------------------------------------------------------------------
// K4: output projection + bias + residual.  X fp32 = CTX@PW^T + PB + RES
// ---------------------------------------------------------------------------
__global__ __launch_bounds__(256) void k_projo(const ushort* __restrict__ CTX,
                                               const float* __restrict__ PW,
                                               const float* __restrict__ PB,
                                               const float* __restrict__ RES,
                                               float* __restrict__ X){
  __shared__ bf16x8 Ach[8 * 128];
  __shared__ bf16x8 Bch[8 * 128];
  const int tid = threadIdx.x;
  const int lane = tid & 63, wid = tid >> 6;
  const int g = lane >> 4, c = lane & 15;
  const int row0 = blockIdx.y * 128, col0 = blockIdx.x * 128;
  const int wm = (wid >> 1) * 64, wn = (wid & 1) * 64;

  f32x4 zero = {0.f, 0.f, 0.f, 0.f};
  f32x4 acc[4][4];
  #pragma unroll
  for (int i = 0; i < 4; i++)
    #pragma unroll
    for (int j = 0; j < 4; j++) acc[i][j] = zero;

  for (int k0 = 0; k0 < ND; k0 += 64){
    #pragma unroll
    for (int i = 0; i < 4; i++){
      int e = tid + i * 256;
      int kc = e & 7, m = e >> 3;
      Ach[kc * 128 + m] = *(const bf16x8*)(CTX + (size_t)(row0 + m) * ND + k0 + kc * 8);
    }
    #pragma unroll
    for (int i = 0; i < 4; i++){
      int e = tid + i * 256;
      int kc = e & 7, n = e >> 3;
      const float* src = PW + (size_t)(col0 + n) * ND + k0 + kc * 8;
      floatx4 v0 = *(const floatx4*)src;
      floatx4 v1 = *(const floatx4*)(src + 4);
      P8 p;
      #pragma unroll
      for (int j = 0; j < 4; j++){ p.u[j] = f2b(v0[j]); p.u[4 + j] = f2b(v1[j]); }
      Bch[kc * 128 + n] = p.b;
    }
    __syncthreads();
    bf16x8 bfr[4][2];
    #pragma unroll
    for (int ni = 0; ni < 4; ni++){
      bfr[ni][0] = Bch[(0 + g) * 128 + wn + ni * 16 + c];
      bfr[ni][1] = Bch[(4 + g) * 128 + wn + ni * 16 + c];
    }
    #pragma unroll
    for (int mi = 0; mi < 4; mi++){
      bf16x8 a0 = Ach[(0 + g) * 128 + wm + mi * 16 + c];
      bf16x8 a1 = Ach[(4 + g) * 128 + wm + mi * 16 + c];
      #pragma unroll
      for (int ni = 0; ni < 4; ni++){
        acc[mi][ni] = MFMA(a0, bfr[ni][0], acc[mi][ni]);
        acc[mi][ni] = MFMA(a1, bfr[ni][1], acc[mi][ni]);
      }
    }
    __syncthreads();
  }
  #pragma unroll
  for (int mi = 0; mi < 4; mi++)
    #pragma unroll
    for (int ni = 0; ni < 4; ni++)
      #pragma unroll
      for (int r = 0; r < 4; r++){
        int m = row0 + wm + mi * 16 + g * 4 + r;
        int n = col0 + wn + ni * 16 + c;
        X[(size_t)m * ND + n] = acc[mi][ni][r] + PB[n] + RES[(size_t)m * ND + n];
      }
}

// ---------------------------------------------------------------------------
// K5a/K5b: BatchNorm stats (coalesced two-stage), K5c: apply in place
// ---------------------------------------------------------------------------
__global__ __launch_bounds__(256) void k_bnst1(const float* __restrict__ X,
                                               float* __restrict__ part){
  const int cx = blockIdx.x * 256 + threadIdx.x;
  const int r0 = blockIdx.y * 256;
  float s = 0.f, s2 = 0.f;
  for (int r = 0; r < 256; r++){
    float v = X[(size_t)(r0 + r) * ND + cx];
    s += v; s2 += v * v;
  }
  part[(size_t)(blockIdx.y * 2 + 0) * ND + cx] = s;
  part[(size_t)(blockIdx.y * 2 + 1) * ND + cx] = s2;
}

__global__ __launch_bounds__(256) void k_bnst2(const float* __restrict__ part,
                                               float* __restrict__ MV){
  const int cx = blockIdx.x * 256 + threadIdx.x;
  float s = 0.f, s2 = 0.f;
  #pragma unroll
  for (int i = 0; i < 16; i++){
    s  += part[(size_t)(i * 2 + 0) * ND + cx];
    s2 += part[(size_t)(i * 2 + 1) * ND + cx];
  }
  float mean = s * (1.f / (NB * NL));
  float var = s2 * (1.f / (NB * NL)) - mean * mean;
  MV[cx] = mean;
  MV[ND + cx] = rsqrtf(var + 1e-5f);
}

__global__ __launch_bounds__(256) void k_bnapply(float* __restrict__ X,
                                                 const float* __restrict__ MV,
                                                 const float* __restrict__ G,
                                                 const float* __restrict__ Bt){
  const int idx = blockIdx.x * 256 + threadIdx.x;
  const size_t base = (size_t)idx * 8;
  const int d0 = (int)(base & (ND - 1));
  floatx4 x0 = *(const floatx4*)(X + base);
  floatx4 x1 = *(const floatx4*)(X + base + 4);
  floatx4 o0, o1;
  #pragma unroll
  for (int e = 0; e < 4; e++){
    int d = d0 + e;
    o0[e] = (x0[e] - MV[d]) * MV[ND + d] * G[d] + Bt[d];
    int d2 = d0 + 4 + e;
    o1[e] = (x1[e] - MV[d2]) * MV[ND + d2] * G[d2] + Bt[d2];
  }
  *(floatx4*)(X + base) = o0;
  *(floatx4*)(X + base + 4) = o1;
}

// ---------------------------------------------------------------------------
extern "C" void kernel_launch(void* const* d_in, const int* in_sizes, int n_in,
                              void* d_out, int out_size, void* d_ws, size_t ws_size,
                              hipStream_t stream){
  const float* q      = (const float*)d_in[0];
  const float* k      = (const float*)d_in[1];
  const float* v      = (const float*)d_in[2];
  const int*   mask   = (const int*)d_in[3];
  const float* w_qs   = (const float*)d_in[4];
  const float* w_ks   = (const float*)d_in[5];
  const float* w_vs   = (const float*)d_in[6];
  const float* proj_w = (const float*)d_in[7];
  const float* proj_b = (const float*)d_in[8];
  const float* gamma  = (const float*)d_in[9];
  const float* beta   = (const float*)d_in[10];

  float* out_x   = (float*)d_out;
  float* out_att = out_x + (size_t)NB * NL * ND;

  char* ws = (char*)d_ws;
  ushort* qh  = (ushort*)(ws);                       // 8 MB
  ushort* kh  = (ushort*)(ws + (8u  << 20));         // 8 MB
  ushort* vh  = (ushort*)(ws + (16u << 20));         // 8 MB
  ushort* ctx = (ushort*)(ws + (24u << 20));         // 8 MB
  unsigned long long* mb = (unsigned long long*)(ws + (33u << 20));  // 512 KB
  float*  part = (float*)(ws + (34u << 20));         // 128 KB
  float*  mv   = (float*)(ws + (35u << 20));         // 8 KB

  dim3 blk(256);
  k_maskpack<<<dim3(NB * NL * NL / 256), blk, 0, stream>>>(mask, mb);
  k_projm<<<dim3(8, 32), blk, 0, stream>>>(q, w_qs, qh);
  k_projm<<<dim3(8, 32), blk, 0, stream>>>(k, w_ks, kh);
  k_projm<<<dim3(8, 32), blk, 0, stream>>>(v, w_vs, vh);
  k_attn<<<dim3(16, NH * NB), blk, 0, stream>>>(qh, kh, vh, (const unsigned*)mb, out_att, ctx);
  k_projo<<<dim3(8, 32), blk, 0, stream>>>(ctx, proj_w, proj_b, q, out_x);
  k_bnst1<<<dim3(4, 16), blk, 0, stream>>>(out_x, part);
  k_bnst2<<<dim3(4), blk, 0, stream>>>(part, mv);
  k_bnapply<<<dim3(NB * NL * ND / 8 / 256), blk, 0, stream>>>(out_x, mv, gamma, beta);
}

// Round 6
// 293.275 us; speedup vs baseline: 8.5297x; 1.4037x over previous
//
#include <hip/hip_runtime.h>

typedef unsigned short ushort;
typedef __attribute__((ext_vector_type(4))) float floatx4;
typedef __bf16 bf16x8 __attribute__((ext_vector_type(8)));
typedef __bf16 bf16x4 __attribute__((ext_vector_type(4)));
typedef float f32x4 __attribute__((ext_vector_type(4)));

constexpr int NB = 4;     // batch
constexpr int NL = 1024;  // seq len
constexpr int ND = 1024;  // d_model
constexpr int NH = 16;    // heads
constexpr int NDK = 64;   // d_k = d_v

union P8 { bf16x8 b; ushort u[8]; };
union B4 { bf16x4 v; unsigned long long ll; };

__device__ __forceinline__ void st_bf(ushort* dst, float f){
  union { __bf16 h; ushort u; } z; z.h = (__bf16)f; *dst = z.u;
}

#define MFMA(a,b,c) __builtin_amdgcn_mfma_f32_16x16x32_bf16((a),(b),(c),0,0,0)

// ---------------------------------------------------------------------------
// K0: pack mask int32 -> bits.  One thread per mask element; 64-lane ballot.
// ---------------------------------------------------------------------------
__global__ __launch_bounds__(256) void k_maskpack(const int* __restrict__ M,
                                                  unsigned long long* __restrict__ MB){
  const int gid = blockIdx.x * 256 + threadIdx.x;
  const int widx = gid >> 6;
  const int l = gid & 63;
  int m = M[(size_t)widx * 64 + l];
  unsigned long long bal = __ballot(m != 0);
  if (l == 0) MB[widx] = bal;
}

// ---------------------------------------------------------------------------
// K1: MFMA projection.  OUT(H*B, L, 64) bf16 = X(4096,1024) @ W(H,1024,64)
// ---------------------------------------------------------------------------
__global__ __launch_bounds__(256) void k_projm(const float* __restrict__ X,
                                               const float* __restrict__ W,
                                               ushort* __restrict__ OUT){
  __shared__ bf16x8 Ach[8 * 128];
  __shared__ bf16x8 Bch[8 * 128];
  const int tid = threadIdx.x;
  const int lane = tid & 63, wid = tid >> 6;
  const int g = lane >> 4, c = lane & 15;
  const int row0 = blockIdx.y * 128, col0 = blockIdx.x * 128;
  const int wm = (wid >> 1) * 64, wn = (wid & 1) * 64;

  f32x4 zero = {0.f, 0.f, 0.f, 0.f};
  f32x4 acc[4][4];
  #pragma unroll
  for (int i = 0; i < 4; i++)
    #pragma unroll
    for (int j = 0; j < 4; j++) acc[i][j] = zero;

  for (int k0 = 0; k0 < ND; k0 += 64){
    #pragma unroll
    for (int i = 0; i < 4; i++){
      int e = tid + i * 256;
      int kc = e & 7, m = e >> 3;
      const float* src = X + (size_t)(row0 + m) * ND + k0 + kc * 8;
      floatx4 v0 = *(const floatx4*)src;
      floatx4 v1 = *(const floatx4*)(src + 4);
      bf16x8 pb;
      #pragma unroll
      for (int j = 0; j < 4; j++){ pb[j] = (__bf16)v0[j]; pb[4 + j] = (__bf16)v1[j]; }
      Ach[kc * 128 + m] = pb;
    }
    {
      int n = tid & 127;
      int hh = (col0 + n) >> 6, dk = (col0 + n) & 63;
      #pragma unroll
      for (int i = 0; i < 4; i++){
        int kc = i * 2 + (tid >> 7);
        bf16x8 pb;
        #pragma unroll
        for (int j = 0; j < 8; j++)
          pb[j] = (__bf16)W[((size_t)hh * ND + k0 + kc * 8 + j) * NDK + dk];
        Bch[kc * 128 + n] = pb;
      }
    }
    __syncthreads();
    bf16x8 bfr[4][2];
    #pragma unroll
    for (int ni = 0; ni < 4; ni++){
      bfr[ni][0] = Bch[(0 + g) * 128 + wn + ni * 16 + c];
      bfr[ni][1] = Bch[(4 + g) * 128 + wn + ni * 16 + c];
    }
    #pragma unroll
    for (int mi = 0; mi < 4; mi++){
      bf16x8 a0 = Ach[(0 + g) * 128 + wm + mi * 16 + c];
      bf16x8 a1 = Ach[(4 + g) * 128 + wm + mi * 16 + c];
      #pragma unroll
      for (int ni = 0; ni < 4; ni++){
        acc[mi][ni] = MFMA(a0, bfr[ni][0], acc[mi][ni]);
        acc[mi][ni] = MFMA(a1, bfr[ni][1], acc[mi][ni]);
      }
    }
    __syncthreads();
  }
  #pragma unroll
  for (int mi = 0; mi < 4; mi++){
    #pragma unroll
    for (int ni = 0; ni < 4; ni++){
      #pragma unroll
      for (int r = 0; r < 4; r++){
        int m = row0 + wm + mi * 16 + g * 4 + r;
        int n = col0 + wn + ni * 16 + c;
        int bb = m >> 10, ls = m & 1023;
        int hh = n >> 6, dk = n & 63;
        st_bf(OUT + (((size_t)hh * NB + bb) * NL + ls) * NDK + dk, acc[mi][ni][r]);
      }
    }
  }
}

// ---------------------------------------------------------------------------
// K2: fused attention (swapped QK^T).  Pass 1: denominators; pass 2: normalized
// p -> fp32 attns + bf16 p -> LDS -> PV.  K tiles staged in LDS with XOR
// swizzle (row stride 128B would be 16-way conflict); mask words in LDS.
// Block = 64 q rows, one hb; 4 waves; grid 16 x 64.
// ---------------------------------------------------------------------------
__global__ __launch_bounds__(256, 4) void k_attn(const ushort* __restrict__ QH,
                                                 const ushort* __restrict__ KH,
                                                 const ushort* __restrict__ VH,
                                                 const unsigned* __restrict__ MB,
                                                 float* __restrict__ ATT,
                                                 ushort* __restrict__ CTX){
  __shared__ bf16x8 Kch[512];        // [sr][kc^(sr&7)] 16B entries, one 64-s tile
  __shared__ bf16x8 Vch[512];        // [kc][dv]
  __shared__ ushort Ps[4][16][72];   // per-wave P tile
  __shared__ unsigned Ms[64 * 33];   // mask words, stride 33 (conflict-free)
  const int tid = threadIdx.x;
  const int lane = tid & 63, wid = tid >> 6;
  const int g = lane >> 4, c = lane & 15;
  const int q0 = blockIdx.x * 64;
  const int hb = blockIdx.y;
  const int h = hb >> 2, b = hb & 3;

  const int q = q0 + wid * 16 + c;
  const size_t qkbase = (size_t)hb * NL;

  bf16x8 qf0 = *(const bf16x8*)(QH + (qkbase + q) * NDK + g * 8);
  bf16x8 qf1 = *(const bf16x8*)(QH + (qkbase + q) * NDK + 32 + g * 8);

  // preload mask words for this block's 64 q rows (64 x 32 words)
  {
    const unsigned* mbase = MB + ((size_t)(b << 10) + q0) * 32;
    #pragma unroll
    for (int i = 0; i < 8; i++){
      int idx = tid + i * 256;
      int ql = idx >> 5, word = idx & 31;
      Ms[ql * 33 + word] = mbase[ql * 32 + word];
    }
  }
  const int ql = wid * 16 + c;
  const int mg = g * 4;

  // ---- pass 1: denominators ----
  float rs = 0.f;
  for (int t = 0; t < 16; ++t){
    __syncthreads();
    const ushort* ksrc = KH + (qkbase + t * 64) * NDK;
    #pragma unroll
    for (int i = 0; i < 2; i++){
      int idx = tid * 2 + i;
      int sr = idx >> 3, kc = idx & 7;
      Kch[sr * 8 + (kc ^ (sr & 7))] = *(const bf16x8*)(ksrc + idx * 8);
    }
    __syncthreads();
    #pragma unroll
    for (int sub2 = 0; sub2 < 4; ++sub2){
      int s = sub2 * 16 + c;
      bf16x8 kf0 = Kch[s * 8 + (g ^ (s & 7))];
      bf16x8 kf1 = Kch[s * 8 + ((4 + g) ^ (s & 7))];
      f32x4 a = {0.f, 0.f, 0.f, 0.f};
      a = MFMA(kf0, qf0, a);
      a = MFMA(kf1, qf1, a);
      unsigned w = Ms[ql * 33 + t * 2 + (sub2 >> 1)];
      unsigned bits4 = (w >> (((sub2 & 1) << 4) + mg)) & 0xFu;
      #pragma unroll
      for (int r = 0; r < 4; r++)
        rs += ((bits4 >> r) & 1u) ? 0.f : __expf(a[r] * (1.f / 32.f));
    }
  }
  rs += __shfl_xor(rs, 16);
  rs += __shfl_xor(rs, 32);
  const float invd = 1.f / rs;

  // ---- pass 2: attns write + PV ----
  f32x4 zero = {0.f, 0.f, 0.f, 0.f};
  f32x4 acc[4];
  #pragma unroll
  for (int i = 0; i < 4; i++) acc[i] = zero;

  for (int t = 0; t < 16; ++t){
    __syncthreads();
    const ushort* ksrc = KH + (qkbase + t * 64) * NDK;
    #pragma unroll
    for (int i = 0; i < 2; i++){
      int idx = tid * 2 + i;
      int sr = idx >> 3, kc = idx & 7;
      Kch[sr * 8 + (kc ^ (sr & 7))] = *(const bf16x8*)(ksrc + idx * 8);
    }
    #pragma unroll
    for (int i = 0; i < 2; i++){
      int idx = tid * 2 + i;
      int kc = idx >> 6, dv = idx & 63;
      P8 p;
      #pragma unroll
      for (int j = 0; j < 8; j++)
        p.u[j] = VH[(qkbase + t * 64 + kc * 8 + j) * NDK + dv];
      Vch[kc * 64 + dv] = p.b;
    }
    __syncthreads();
    #pragma unroll
    for (int sub2 = 0; sub2 < 4; ++sub2){
      int s = sub2 * 16 + c;
      bf16x8 kf0 = Kch[s * 8 + (g ^ (s & 7))];
      bf16x8 kf1 = Kch[s * 8 + ((4 + g) ^ (s & 7))];
      f32x4 a = {0.f, 0.f, 0.f, 0.f};
      a = MFMA(kf0, qf0, a);
      a = MFMA(kf1, qf1, a);
      unsigned w = Ms[ql * 33 + t * 2 + (sub2 >> 1)];
      unsigned bits4 = (w >> (((sub2 & 1) << 4) + mg)) & 0xFu;
      floatx4 pn;
      B4 pw;
      #pragma unroll
      for (int r = 0; r < 4; r++){
        float p = ((bits4 >> r) & 1u) ? 0.f : __expf(a[r] * (1.f / 32.f)) * invd;
        pn[r] = p;
        pw.v[r] = (__bf16)p;
      }
      *(floatx4*)(ATT + ((size_t)hb * NL + q) * NL + (t * 4 + sub2) * 16 + g * 4) = pn;
      *(unsigned long long*)&Ps[wid][c][sub2 * 16 + g * 4] = pw.ll;
    }
    #pragma unroll
    for (int ss = 0; ss < 2; ++ss){
      bf16x8 afr = *(bf16x8*)&Ps[wid][c][ss * 32 + g * 8];
      #pragma unroll
      for (int ni = 0; ni < 4; ni++){
        bf16x8 vfr = Vch[(ss * 4 + g) * 64 + ni * 16 + c];
        acc[ni] = MFMA(afr, vfr, acc[ni]);
      }
    }
  }

  #pragma unroll
  for (int ni = 0; ni < 4; ni++)
    #pragma unroll
    for (int r = 0; r < 4; r++){
      int qq = q0 + wid * 16 + g * 4 + r;
      int dv = ni * 16 + c;
      st_bf(CTX + ((size_t)b * NL + qq) * ND + h * NDK + dv, acc[ni][r]);
    }
}

// ---------------------------------------------------------------------------
// K4: output projection + bias + residual.  X fp32 = CTX@PW^T + PB + RES
// ---------------------------------------------------------------------------
__global__ __launch_bounds__(256) void k_projo(const ushort* __restrict__ CTX,
                                               const float* __restrict__ PW,
                                               const float* __restrict__ PB,
                                               const float* __restrict__ RES,
                                               float* __restrict__ X){
  __shared__ bf16x8 Ach[8 * 128];
  __shared__ bf16x8 Bch[8 * 128];
  const int tid = threadIdx.x;
  const int lane = tid & 63, wid = tid >> 6;
  const int g = lane >> 4, c = lane & 15;
  const int row0 = blockIdx.y * 128, col0 = blockIdx.x * 128;
  const int wm = (wid >> 1) * 64, wn = (wid & 1) * 64;

  f32x4 zero = {0.f, 0.f, 0.f, 0.f};
  f32x4 acc[4][4];
  #pragma unroll
  for (int i = 0; i < 4; i++)
    #pragma unroll
    for (int j = 0; j < 4; j++) acc[i][j] = zero;

  for (int k0 = 0; k0 < ND; k0 += 64){
    #pragma unroll
    for (int i = 0; i < 4; i++){
      int e = tid + i * 256;
      int kc = e & 7, m = e >> 3;
      Ach[kc * 128 + m] = *(const bf16x8*)(CTX + (size_t)(row0 + m) * ND + k0 + kc * 8);
    }
    #pragma unroll
    for (int i = 0; i < 4; i++){
      int e = tid + i * 256;
      int kc = e & 7, n = e >> 3;
      const float* src = PW + (size_t)(col0 + n) * ND + k0 + kc * 8;
      floatx4 v0 = *(const floatx4*)src;
      floatx4 v1 = *(const floatx4*)(src + 4);
      bf16x8 pb;
      #pragma unroll
      for (int j = 0; j < 4; j++){ pb[j] = (__bf16)v0[j]; pb[4 + j] = (__bf16)v1[j]; }
      Bch[kc * 128 + n] = pb;
    }
    __syncthreads();
    bf16x8 bfr[4][2];
    #pragma unroll
    for (int ni = 0; ni < 4; ni++){
      bfr[ni][0] = Bch[(0 + g) * 128 + wn + ni * 16 + c];
      bfr[ni][1] = Bch[(4 + g) * 128 + wn + ni * 16 + c];
    }
    #pragma unroll
    for (int mi = 0; mi < 4; mi++){
      bf16x8 a0 = Ach[(0 + g) * 128 + wm + mi * 16 + c];
      bf16x8 a1 = Ach[(4 + g) * 128 + wm + mi * 16 + c];
      #pragma unroll
      for (int ni = 0; ni < 4; ni++){
        acc[mi][ni] = MFMA(a0, bfr[ni][0], acc[mi][ni]);
        acc[mi][ni] = MFMA(a1, bfr[ni][1], acc[mi][ni]);
      }
    }
    __syncthreads();
  }
  #pragma unroll
  for (int mi = 0; mi < 4; mi++)
    #pragma unroll
    for (int ni = 0; ni < 4; ni++)
      #pragma unroll
      for (int r = 0; r < 4; r++){
        int m = row0 + wm + mi * 16 + g * 4 + r;
        int n = col0 + wn + ni * 16 + c;
        X[(size_t)m * ND + n] = acc[mi][ni][r] + PB[n] + RES[(size_t)m * ND + n];
      }
}

// ---------------------------------------------------------------------------
// K5a/K5b: BatchNorm stats (coalesced two-stage), K5c: apply in place
// ---------------------------------------------------------------------------
__global__ __launch_bounds__(256) void k_bnst1(const float* __restrict__ X,
                                               float* __restrict__ part){
  const int cx = blockIdx.x * 256 + threadIdx.x;
  const int r0 = blockIdx.y * 256;
  float s = 0.f, s2 = 0.f;
  for (int r = 0; r < 256; r++){
    float v = X[(size_t)(r0 + r) * ND + cx];
    s += v; s2 += v * v;
  }
  part[(size_t)(blockIdx.y * 2 + 0) * ND + cx] = s;
  part[(size_t)(blockIdx.y * 2 + 1) * ND + cx] = s2;
}

__global__ __launch_bounds__(256) void k_bnst2(const float* __restrict__ part,
                                               float* __restrict__ MV){
  const int cx = blockIdx.x * 256 + threadIdx.x;
  float s = 0.f, s2 = 0.f;
  #pragma unroll
  for (int i = 0; i < 16; i++){
    s  += part[(size_t)(i * 2 + 0) * ND + cx];
    s2 += part[(size_t)(i * 2 + 1) * ND + cx];
  }
  float mean = s * (1.f / (NB * NL));
  float var = s2 * (1.f / (NB * NL)) - mean * mean;
  MV[cx] = mean;
  MV[ND + cx] = rsqrtf(var + 1e-5f);
}

__global__ __launch_bounds__(256) void k_bnapply(float* __restrict__ X,
                                                 const float* __restrict__ MV,
                                                 const float* __restrict__ G,
                                                 const float* __restrict__ Bt){
  const int idx = blockIdx.x * 256 + threadIdx.x;
  const size_t base = (size_t)idx * 8;
  const int d0 = (int)(base & (ND - 1));
  floatx4 x0 = *(const floatx4*)(X + base);
  floatx4 x1 = *(const floatx4*)(X + base + 4);
  floatx4 o0, o1;
  #pragma unroll
  for (int e = 0; e < 4; e++){
    int d = d0 + e;
    o0[e] = (x0[e] - MV[d]) * MV[ND + d] * G[d] + Bt[d];
    int d2 = d0 + 4 + e;
    o1[e] = (x1[e] - MV[d2]) * MV[ND + d2] * G[d2] + Bt[d2];
  }
  *(floatx4*)(X + base) = o0;
  *(floatx4*)(X + base + 4) = o1;
}

// ---------------------------------------------------------------------------
extern "C" void kernel_launch(void* const* d_in, const int* in_sizes, int n_in,
                              void* d_out, int out_size, void* d_ws, size_t ws_size,
                              hipStream_t stream){
  const float* q      = (const float*)d_in[0];
  const float* k      = (const float*)d_in[1];
  const float* v      = (const float*)d_in[2];
  const int*   mask   = (const int*)d_in[3];
  const float* w_qs   = (const float*)d_in[4];
  const float* w_ks   = (const float*)d_in[5];
  const float* w_vs   = (const float*)d_in[6];
  const float* proj_w = (const float*)d_in[7];
  const float* proj_b = (const float*)d_in[8];
  const float* gamma  = (const float*)d_in[9];
  const float* beta   = (const float*)d_in[10];

  float* out_x   = (float*)d_out;
  float* out_att = out_x + (size_t)NB * NL * ND;

  char* ws = (char*)d_ws;
  ushort* qh  = (ushort*)(ws);                       // 8 MB
  ushort* kh  = (ushort*)(ws + (8u  << 20));         // 8 MB
  ushort* vh  = (ushort*)(ws + (16u << 20));         // 8 MB
  ushort* ctx = (ushort*)(ws + (24u << 20));         // 8 MB
  unsigned long long* mb = (unsigned long long*)(ws + (33u << 20));  // 512 KB
  float*  part = (float*)(ws + (34u << 20));         // 128 KB
  float*  mv   = (float*)(ws + (35u << 20));         // 8 KB

  dim3 blk(256);
  k_maskpack<<<dim3(NB * NL * NL / 256), blk, 0, stream>>>(mask, mb);
  k_projm<<<dim3(8, 32), blk, 0, stream>>>(q, w_qs, qh);
  k_projm<<<dim3(8, 32), blk, 0, stream>>>(k, w_ks, kh);
  k_projm<<<dim3(8, 32), blk, 0, stream>>>(v, w_vs, vh);
  k_attn<<<dim3(16, NH * NB), blk, 0, stream>>>(qh, kh, vh, (const unsigned*)mb, out_att, ctx);
  k_projo<<<dim3(8, 32), blk, 0, stream>>>(ctx, proj_w, proj_b, q, out_x);
  k_bnst1<<<dim3(4, 16), blk, 0, stream>>>(out_x, part);
  k_bnst2<<<dim3(4), blk, 0, stream>>>(part, mv);
  k_bnapply<<<dim3(NB * NL * ND / 8 / 256), blk, 0, stream>>>(out_x, mv, gamma, beta);
}

// Round 7
// 232.300 us; speedup vs baseline: 10.7687x; 1.2625x over previous
//
#include <hip/hip_runtime.h>

typedef unsigned short ushort;
typedef __attribute__((ext_vector_type(4))) float floatx4;
typedef __bf16 bf16x8 __attribute__((ext_vector_type(8)));
typedef __bf16 bf16x4 __attribute__((ext_vector_type(4)));
typedef float f32x4 __attribute__((ext_vector_type(4)));

constexpr int NB = 4;     // batch
constexpr int NL = 1024;  // seq len
constexpr int ND = 1024;  // d_model
constexpr int NH = 16;    // heads
constexpr int NDK = 64;   // d_k = d_v

union P8 { bf16x8 b; ushort u[8]; };
union B4 { bf16x4 v; unsigned long long ll; };

__device__ __forceinline__ void st_bf(ushort* dst, float f){
  union { __bf16 h; ushort u; } z; z.h = (__bf16)f; *dst = z.u;
}

#define MFMA(a,b,c) __builtin_amdgcn_mfma_f32_16x16x32_bf16((a),(b),(c),0,0,0)

// ---------------------------------------------------------------------------
// K0a: cast q/k/v/proj_w fp32 -> bf16.  grid (2048,1,4); z==3 -> proj_w (512 blk)
// ---------------------------------------------------------------------------
__global__ __launch_bounds__(256) void k_cast(const float* __restrict__ q,
                                              const float* __restrict__ k,
                                              const float* __restrict__ v,
                                              const float* __restrict__ pw,
                                              ushort* __restrict__ qb,
                                              ushort* __restrict__ kb,
                                              ushort* __restrict__ vb,
                                              ushort* __restrict__ pwb){
  const int z = blockIdx.z;
  if (z == 3 && blockIdx.x >= 512) return;
  const float* src = (z == 0) ? q : (z == 1) ? k : (z == 2) ? v : pw;
  ushort* dst = (z == 0) ? qb : (z == 1) ? kb : (z == 2) ? vb : pwb;
  const size_t base = ((size_t)blockIdx.x * 256 + threadIdx.x) * 8;
  floatx4 v0 = *(const floatx4*)(src + base);
  floatx4 v1 = *(const floatx4*)(src + base + 4);
  bf16x8 o;
  #pragma unroll
  for (int j = 0; j < 4; j++){ o[j] = (__bf16)v0[j]; o[4 + j] = (__bf16)v1[j]; }
  *(bf16x8*)(dst + base) = o;
}

// ---------------------------------------------------------------------------
// K0b: transpose-cast head weights.  W(h,1024,64) fp32 -> WT(h,64,1024) bf16.
// grid (16 k-tiles, 16 heads, 3 arrays)
// ---------------------------------------------------------------------------
__global__ __launch_bounds__(256) void k_wT(const float* __restrict__ w0,
                                            const float* __restrict__ w1,
                                            const float* __restrict__ w2,
                                            ushort* __restrict__ t0,
                                            ushort* __restrict__ t1,
                                            ushort* __restrict__ t2){
  __shared__ ushort T[64][65];
  const int z = blockIdx.z;
  const float* src = (z == 0) ? w0 : (z == 1) ? w1 : w2;
  ushort* dst = (z == 0) ? t0 : (z == 1) ? t1 : t2;
  const int h = blockIdx.y, k0 = blockIdx.x * 64;
  const int tid = threadIdx.x;
  const int qd = tid >> 6, lo = tid & 63;
  #pragma unroll
  for (int i = 0; i < 16; i++){
    int kl = qd + i * 4;
    float f = src[((size_t)h * 1024 + k0 + kl) * 64 + lo];
    union { __bf16 h2; ushort u; } zz; zz.h2 = (__bf16)f;
    T[kl][lo] = zz.u;
  }
  __syncthreads();
  #pragma unroll
  for (int i = 0; i < 16; i++){
    int dk = qd + i * 4;
    dst[((size_t)h * 64 + dk) * 1024 + k0 + lo] = T[lo][dk];
  }
}

// ---------------------------------------------------------------------------
// K0c: pack mask int32 -> bits (64-lane ballot).
// ---------------------------------------------------------------------------
__global__ __launch_bounds__(256) void k_maskpack(const int* __restrict__ M,
                                                  unsigned long long* __restrict__ MB){
  const int gid = blockIdx.x * 256 + threadIdx.x;
  const int widx = gid >> 6;
  const int l = gid & 63;
  int m = M[(size_t)widx * 64 + l];
  unsigned long long bal = __ballot(m != 0);
  if (l == 0) MB[widx] = bal;
}

// ---------------------------------------------------------------------------
// K1: projection. OUT(H*B,L,64) bf16 = Xb(4096,1024)bf16 @ WT(h,64,1024)bf16.
// XOR bank swizzle on LDS entries; XCD-aware tile remap (256 wg = 8 x 32).
// ---------------------------------------------------------------------------
__global__ __launch_bounds__(256) void k_projm(const ushort* __restrict__ Xb,
                                               const ushort* __restrict__ WT,
                                               ushort* __restrict__ OUT){
  __shared__ bf16x8 Ach[8 * 128];
  __shared__ bf16x8 Bch[8 * 128];
  const int tid = threadIdx.x;
  const int lane = tid & 63, wid = tid >> 6;
  const int g = lane >> 4, c = lane & 15;
  const int d = blockIdx.y * 8 + blockIdx.x;
  const int tile = (d & 7) * 32 + (d >> 3);
  const int row0 = (tile >> 3) * 128, col0 = (tile & 7) * 128;
  const int wm = (wid >> 1) * 64, wn = (wid & 1) * 64;

  f32x4 zero = {0.f, 0.f, 0.f, 0.f};
  f32x4 acc[4][4];
  #pragma unroll
  for (int i = 0; i < 4; i++)
    #pragma unroll
    for (int j = 0; j < 4; j++) acc[i][j] = zero;

  for (int k0 = 0; k0 < ND; k0 += 64){
    #pragma unroll
    for (int i = 0; i < 4; i++){
      int e = tid + i * 256;
      int kc = e & 7, m = e >> 3;
      Ach[kc * 128 + (m ^ kc)] = *(const bf16x8*)(Xb + (size_t)(row0 + m) * ND + k0 + kc * 8);
    }
    #pragma unroll
    for (int i = 0; i < 4; i++){
      int e = tid + i * 256;
      int kc = e & 7, n = e >> 3;
      int hh = (col0 + n) >> 6, dk = (col0 + n) & 63;
      Bch[kc * 128 + (n ^ kc)] = *(const bf16x8*)(WT + ((size_t)(hh << 6) + dk) * 1024 + k0 + kc * 8);
    }
    __syncthreads();
    bf16x8 bfr[4][2];
    #pragma unroll
    for (int ni = 0; ni < 4; ni++){
      int n = wn + ni * 16 + c;
      bfr[ni][0] = Bch[g * 128 + (n ^ g)];
      bfr[ni][1] = Bch[(4 + g) * 128 + (n ^ (4 + g))];
    }
    #pragma unroll
    for (int mi = 0; mi < 4; mi++){
      int m = wm + mi * 16 + c;
      bf16x8 a0 = Ach[g * 128 + (m ^ g)];
      bf16x8 a1 = Ach[(4 + g) * 128 + (m ^ (4 + g))];
      #pragma unroll
      for (int ni = 0; ni < 4; ni++){
        acc[mi][ni] = MFMA(a0, bfr[ni][0], acc[mi][ni]);
        acc[mi][ni] = MFMA(a1, bfr[ni][1], acc[mi][ni]);
      }
    }
    __syncthreads();
  }
  #pragma unroll
  for (int mi = 0; mi < 4; mi++){
    #pragma unroll
    for (int ni = 0; ni < 4; ni++){
      #pragma unroll
      for (int r = 0; r < 4; r++){
        int m = row0 + wm + mi * 16 + g * 4 + r;
        int n = col0 + wn + ni * 16 + c;
        int bb = m >> 10, ls = m & 1023;
        int hh = n >> 6, dk = n & 63;
        st_bf(OUT + (((size_t)hh * NB + bb) * NL + ls) * NDK + dk, acc[mi][ni][r]);
      }
    }
  }
}

// ---------------------------------------------------------------------------
// K2: fused attention (swapped QK^T), two passes; K tiles LDS-staged with XOR
// swizzle; mask words in LDS; XCD remap so each XCD owns 8 whole hb groups.
// ---------------------------------------------------------------------------
__global__ __launch_bounds__(256, 4) void k_attn(const ushort* __restrict__ QH,
                                                 const ushort* __restrict__ KH,
                                                 const ushort* __restrict__ VH,
                                                 const unsigned* __restrict__ MB,
                                                 float* __restrict__ ATT,
                                                 ushort* __restrict__ CTX){
  __shared__ bf16x8 Kch[512];        // [sr][kc^(sr&7)]
  __shared__ bf16x8 Vch[512];        // [kc][dv]
  __shared__ ushort Ps[4][16][72];
  __shared__ unsigned Ms[64 * 33];
  const int tid = threadIdx.x;
  const int lane = tid & 63, wid = tid >> 6;
  const int g = lane >> 4, c = lane & 15;
  const int d = blockIdx.y * 16 + blockIdx.x;
  const int tile = (d & 7) * 128 + (d >> 3);
  const int hb = tile >> 4;
  const int q0 = (tile & 15) * 64;
  const int h = hb >> 2, b = hb & 3;

  const int q = q0 + wid * 16 + c;
  const size_t qkbase = (size_t)hb * NL;

  bf16x8 qf0 = *(const bf16x8*)(QH + (qkbase + q) * NDK + g * 8);
  bf16x8 qf1 = *(const bf16x8*)(QH + (qkbase + q) * NDK + 32 + g * 8);

  {
    const unsigned* mbase = MB + ((size_t)(b << 10) + q0) * 32;
    #pragma unroll
    for (int i = 0; i < 8; i++){
      int idx = tid + i * 256;
      int ql2 = idx >> 5, word = idx & 31;
      Ms[ql2 * 33 + word] = mbase[ql2 * 32 + word];
    }
  }
  const int ql = wid * 16 + c;
  const int mg = g * 4;

  // ---- pass 1: denominators ----
  float rs = 0.f;
  for (int t = 0; t < 16; ++t){
    __syncthreads();
    const ushort* ksrc = KH + (qkbase + t * 64) * NDK;
    #pragma unroll
    for (int i = 0; i < 2; i++){
      int idx = tid * 2 + i;
      int sr = idx >> 3, kc = idx & 7;
      Kch[sr * 8 + (kc ^ (sr & 7))] = *(const bf16x8*)(ksrc + idx * 8);
    }
    __syncthreads();
    #pragma unroll
    for (int sub2 = 0; sub2 < 4; ++sub2){
      int s = sub2 * 16 + c;
      bf16x8 kf0 = Kch[s * 8 + (g ^ (s & 7))];
      bf16x8 kf1 = Kch[s * 8 + ((4 + g) ^ (s & 7))];
      f32x4 a = {0.f, 0.f, 0.f, 0.f};
      a = MFMA(kf0, qf0, a);
      a = MFMA(kf1, qf1, a);
      unsigned w = Ms[ql * 33 + t * 2 + (sub2 >> 1)];
      unsigned bits4 = (w >> (((sub2 & 1) << 4) + mg)) & 0xFu;
      #pragma unroll
      for (int r = 0; r < 4; r++)
        rs += ((bits4 >> r) & 1u) ? 0.f : __expf(a[r] * (1.f / 32.f));
    }
  }
  rs += __shfl_xor(rs, 16);
  rs += __shfl_xor(rs, 32);
  const float invd = 1.f / rs;

  // ---- pass 2: attns write + PV ----
  f32x4 zero = {0.f, 0.f, 0.f, 0.f};
  f32x4 acc[4];
  #pragma unroll
  for (int i = 0; i < 4; i++) acc[i] = zero;

  for (int t = 0; t < 16; ++t){
    __syncthreads();
    const ushort* ksrc = KH + (qkbase + t * 64) * NDK;
    #pragma unroll
    for (int i = 0; i < 2; i++){
      int idx = tid * 2 + i;
      int sr = idx >> 3, kc = idx & 7;
      Kch[sr * 8 + (kc ^ (sr & 7))] = *(const bf16x8*)(ksrc + idx * 8);
    }
    #pragma unroll
    for (int i = 0; i < 2; i++){
      int idx = tid * 2 + i;
      int kc = idx >> 6, dv = idx & 63;
      P8 p;
      #pragma unroll
      for (int j = 0; j < 8; j++)
        p.u[j] = VH[(qkbase + t * 64 + kc * 8 + j) * NDK + dv];
      Vch[kc * 64 + dv] = p.b;
    }
    __syncthreads();
    #pragma unroll
    for (int sub2 = 0; sub2 < 4; ++sub2){
      int s = sub2 * 16 + c;
      bf16x8 kf0 = Kch[s * 8 + (g ^ (s & 7))];
      bf16x8 kf1 = Kch[s * 8 + ((4 + g) ^ (s & 7))];
      f32x4 a = {0.f, 0.f, 0.f, 0.f};
      a = MFMA(kf0, qf0, a);
      a = MFMA(kf1, qf1, a);
      unsigned w = Ms[ql * 33 + t * 2 + (sub2 >> 1)];
      unsigned bits4 = (w >> (((sub2 & 1) << 4) + mg)) & 0xFu;
      floatx4 pn;
      B4 pw;
      #pragma unroll
      for (int r = 0; r < 4; r++){
        float p = ((bits4 >> r) & 1u) ? 0.f : __expf(a[r] * (1.f / 32.f)) * invd;
        pn[r] = p;
        pw.v[r] = (__bf16)p;
      }
      *(floatx4*)(ATT + ((size_t)hb * NL + q) * NL + (t * 4 + sub2) * 16 + g * 4) = pn;
      *(unsigned long long*)&Ps[wid][c][sub2 * 16 + g * 4] = pw.ll;
    }
    #pragma unroll
    for (int ss = 0; ss < 2; ++ss){
      bf16x8 afr = *(bf16x8*)&Ps[wid][c][ss * 32 + g * 8];
      #pragma unroll
      for (int ni = 0; ni < 4; ni++){
        bf16x8 vfr = Vch[(ss * 4 + g) * 64 + ni * 16 + c];
        acc[ni] = MFMA(afr, vfr, acc[ni]);
      }
    }
  }

  #pragma unroll
  for (int ni = 0; ni < 4; ni++)
    #pragma unroll
    for (int r = 0; r < 4; r++){
      int qq = q0 + wid * 16 + g * 4 + r;
      int dv = ni * 16 + c;
      st_bf(CTX + ((size_t)b * NL + qq) * ND + h * NDK + dv, acc[ni][r]);
    }
}

// ---------------------------------------------------------------------------
// K4: output projection + bias + residual (bf16 A/B, fp32 epilogue)
// ---------------------------------------------------------------------------
__global__ __launch_bounds__(256) void k_projo(const ushort* __restrict__ CTX,
                                               const ushort* __restrict__ PWb,
                                               const float* __restrict__ PB,
                                               const float* __restrict__ RES,
                                               float* __restrict__ X){
  __shared__ bf16x8 Ach[8 * 128];
  __shared__ bf16x8 Bch[8 * 128];
  const int tid = threadIdx.x;
  const int lane = tid & 63, wid = tid >> 6;
  const int g = lane >> 4, c = lane & 15;
  const int d = blockIdx.y * 8 + blockIdx.x;
  const int tile = (d & 7) * 32 + (d >> 3);
  const int row0 = (tile >> 3) * 128, col0 = (tile & 7) * 128;
  const int wm = (wid >> 1) * 64, wn = (wid & 1) * 64;

  f32x4 zero = {0.f, 0.f, 0.f, 0.f};
  f32x4 acc[4][4];
  #pragma unroll
  for (int i = 0; i < 4; i++)
    #pragma unroll
    for (int j = 0; j < 4; j++) acc[i][j] = zero;

  for (int k0 = 0; k0 < ND; k0 += 64){
    #pragma unroll
    for (int i = 0; i < 4; i++){
      int e = tid + i * 256;
      int kc = e & 7, m = e >> 3;
      Ach[kc * 128 + (m ^ kc)] = *(const bf16x8*)(CTX + (size_t)(row0 + m) * ND + k0 + kc * 8);
    }
    #pragma unroll
    for (int i = 0; i < 4; i++){
      int e = tid + i * 256;
      int kc = e & 7, n = e >> 3;
      Bch[kc * 128 + (n ^ kc)] = *(const bf16x8*)(PWb + (size_t)(col0 + n) * 1024 + k0 + kc * 8);
    }
    __syncthreads();
    bf16x8 bfr[4][2];
    #pragma unroll
    for (int ni = 0; ni < 4; ni++){
      int n = wn + ni * 16 + c;
      bfr[ni][0] = Bch[g * 128 + (n ^ g)];
      bfr[ni][1] = Bch[(4 + g) * 128 + (n ^ (4 + g))];
    }
    #pragma unroll
    for (int mi = 0; mi < 4; mi++){
      int m = wm + mi * 16 + c;
      bf16x8 a0 = Ach[g * 128 + (m ^ g)];
      bf16x8 a1 = Ach[(4 + g) * 128 + (m ^ (4 + g))];
      #pragma unroll
      for (int ni = 0; ni < 4; ni++){
        acc[mi][ni] = MFMA(a0, bfr[ni][0], acc[mi][ni]);
        acc[mi][ni] = MFMA(a1, bfr[ni][1], acc[mi][ni]);
      }
    }
    __syncthreads();
  }
  #pragma unroll
  for (int mi = 0; mi < 4; mi++)
    #pragma unroll
    for (int ni = 0; ni < 4; ni++)
      #pragma unroll
      for (int r = 0; r < 4; r++){
        int m = row0 + wm + mi * 16 + g * 4 + r;
        int n = col0 + wn + ni * 16 + c;
        X[(size_t)m * ND + n] = acc[mi][ni][r] + PB[n] + RES[(size_t)m * ND + n];
      }
}

// ---------------------------------------------------------------------------
// K5: BatchNorm stats (two-stage) + apply in place
// ---------------------------------------------------------------------------
__global__ __launch_bounds__(256) void k_bnst1(const float* __restrict__ X,
                                               float* __restrict__ part){
  const int cx = blockIdx.x * 256 + threadIdx.x;
  const int r0 = blockIdx.y * 256;
  float s = 0.f, s2 = 0.f;
  for (int r = 0; r < 256; r++){
    float v = X[(size_t)(r0 + r) * ND + cx];
    s += v; s2 += v * v;
  }
  part[(size_t)(blockIdx.y * 2 + 0) * ND + cx] = s;
  part[(size_t)(blockIdx.y * 2 + 1) * ND + cx] = s2;
}

__global__ __launch_bounds__(256) void k_bnst2(const float* __restrict__ part,
                                               float* __restrict__ MV){
  const int cx = blockIdx.x * 256 + threadIdx.x;
  float s = 0.f, s2 = 0.f;
  #pragma unroll
  for (int i = 0; i < 16; i++){
    s  += part[(size_t)(i * 2 + 0) * ND + cx];
    s2 += part[(size_t)(i * 2 + 1) * ND + cx];
  }
  float mean = s * (1.f / (NB * NL));
  float var = s2 * (1.f / (NB * NL)) - mean * mean;
  MV[cx] = mean;
  MV[ND + cx] = rsqrtf(var + 1e-5f);
}

__global__ __launch_bounds__(256) void k_bnapply(float* __restrict__ X,
                                                 const float* __restrict__ MV,
                                                 const float* __restrict__ G,
                                                 const float* __restrict__ Bt){
  const int idx = blockIdx.x * 256 + threadIdx.x;
  const size_t base = (size_t)idx * 8;
  const int d0 = (int)(base & (ND - 1));
  floatx4 x0 = *(const floatx4*)(X + base);
  floatx4 x1 = *(const floatx4*)(X + base + 4);
  floatx4 o0, o1;
  #pragma unroll
  for (int e = 0; e < 4; e++){
    int d = d0 + e;
    o0[e] = (x0[e] - MV[d]) * MV[ND + d] * G[d] + Bt[d];
    int d2 = d0 + 4 + e;
    o1[e] = (x1[e] - MV[d2]) * MV[ND + d2] * G[d2] + Bt[d2];
  }
  *(floatx4*)(X + base) = o0;
  *(floatx4*)(X + base + 4) = o1;
}

// ---------------------------------------------------------------------------
extern "C" void kernel_launch(void* const* d_in, const int* in_sizes, int n_in,
                              void* d_out, int out_size, void* d_ws, size_t ws_size,
                              hipStream_t stream){
  const float* q      = (const float*)d_in[0];
  const float* k      = (const float*)d_in[1];
  const float* v      = (const float*)d_in[2];
  const int*   mask   = (const int*)d_in[3];
  const float* w_qs   = (const float*)d_in[4];
  const float* w_ks   = (const float*)d_in[5];
  const float* w_vs   = (const float*)d_in[6];
  const float* proj_w = (const float*)d_in[7];
  const float* proj_b = (const float*)d_in[8];
  const float* gamma  = (const float*)d_in[9];
  const float* beta   = (const float*)d_in[10];

  float* out_x   = (float*)d_out;
  float* out_att = out_x + (size_t)NB * NL * ND;

  char* ws = (char*)d_ws;
  ushort* qb  = (ushort*)(ws);                       // 8 MB (reused as ctx)
  ushort* kb  = (ushort*)(ws + (8u  << 20));
  ushort* vb  = (ushort*)(ws + (16u << 20));
  ushort* qh  = (ushort*)(ws + (24u << 20));
  ushort* kh  = (ushort*)(ws + (32u << 20));
  ushort* vh  = (ushort*)(ws + (40u << 20));
  ushort* wqT = (ushort*)(ws + (48u << 20));         // 2 MB each
  ushort* wkT = (ushort*)(ws + (50u << 20));
  ushort* wvT = (ushort*)(ws + (52u << 20));
  ushort* pwb = (ushort*)(ws + (54u << 20));
  unsigned long long* mb = (unsigned long long*)(ws + (56u << 20));  // 512 KB
  float*  part = (float*)(ws + (57u << 20));         // 128 KB
  float*  mv   = (float*)(ws + (58u << 20));         // 8 KB
  ushort* ctx  = qb;                                 // qb dead after its projm

  dim3 blk(256);
  k_cast<<<dim3(2048, 1, 4), blk, 0, stream>>>(q, k, v, proj_w, qb, kb, vb, pwb);
  k_wT<<<dim3(16, 16, 3), blk, 0, stream>>>(w_qs, w_ks, w_vs, wqT, wkT, wvT);
  k_maskpack<<<dim3(NB * NL * NL / 256), blk, 0, stream>>>(mask, mb);
  k_projm<<<dim3(8, 32), blk, 0, stream>>>(qb, wqT, qh);
  k_projm<<<dim3(8, 32), blk, 0, stream>>>(kb, wkT, kh);
  k_projm<<<dim3(8, 32), blk, 0, stream>>>(vb, wvT, vh);
  k_attn<<<dim3(16, NH * NB), blk, 0, stream>>>(qh, kh, vh, (const unsigned*)mb, out_att, ctx);
  k_projo<<<dim3(8, 32), blk, 0, stream>>>(ctx, pwb, proj_b, q, out_x);
  k_bnst1<<<dim3(4, 16), blk, 0, stream>>>(out_x, part);
  k_bnst2<<<dim3(4), blk, 0, stream>>>(part, mv);
  k_bnapply<<<dim3(NB * NL * ND / 8 / 256), blk, 0, stream>>>(out_x, mv, gamma, beta);
}

// Round 8
// 195.036 us; speedup vs baseline: 12.8261x; 1.1911x over previous
//
#include <hip/hip_runtime.h>

typedef unsigned short ushort;
typedef __attribute__((ext_vector_type(4))) float floatx4;
typedef __bf16 bf16x8 __attribute__((ext_vector_type(8)));
typedef __bf16 bf16x4 __attribute__((ext_vector_type(4)));
typedef float f32x4 __attribute__((ext_vector_type(4)));

constexpr int NB = 4;     // batch
constexpr int NL = 1024;  // seq len
constexpr int ND = 1024;  // d_model
constexpr int NH = 16;    // heads
constexpr int NDK = 64;   // d_k = d_v

union B4 { bf16x4 v; unsigned long long ll; };

__device__ __forceinline__ void st_bf(ushort* dst, float f){
  union { __bf16 h; ushort u; } z; z.h = (__bf16)f; *dst = z.u;
}

#define MFMA(a,b,c) __builtin_amdgcn_mfma_f32_16x16x32_bf16((a),(b),(c),0,0,0)

// ---------------------------------------------------------------------------
// K0: merged prep.  Linear block ranges:
//   [0,6656)      cast q/k/v/proj_w fp32 -> bf16 (q:0-2047 k:2048-4095
//                 v:4096-6143 pw:6144-6655)
//   [6656,7424)   transpose-cast w_qs/w_ks/w_vs -> WT(h,64,1024) bf16
//   [7424,11520)  mask int32 -> bit-pack (ballot)
//   11520         zero BN partial sums
// ---------------------------------------------------------------------------
__global__ __launch_bounds__(256) void k_prep(const float* __restrict__ q,
                                              const float* __restrict__ k,
                                              const float* __restrict__ v,
                                              const float* __restrict__ pw,
                                              const float* __restrict__ w0,
                                              const float* __restrict__ w1,
                                              const float* __restrict__ w2,
                                              const int* __restrict__ M,
                                              ushort* __restrict__ qb,
                                              ushort* __restrict__ kb,
                                              ushort* __restrict__ vb,
                                              ushort* __restrict__ pwb,
                                              ushort* __restrict__ t0,
                                              ushort* __restrict__ t1,
                                              ushort* __restrict__ t2,
                                              unsigned long long* __restrict__ MB,
                                              float* __restrict__ part){
  __shared__ ushort T[64][65];
  const int bid = blockIdx.x;
  const int tid = threadIdx.x;

  if (bid < 6656){                      // ---- cast ----
    const int a = (bid < 2048) ? 0 : (bid < 4096) ? 1 : (bid < 6144) ? 2 : 3;
    const int rel = bid - a * 2048;     // pw starts at 6144 = 3*2048
    const float* src = (a == 0) ? q : (a == 1) ? k : (a == 2) ? v : pw;
    ushort* dst = (a == 0) ? qb : (a == 1) ? kb : (a == 2) ? vb : pwb;
    const size_t base = ((size_t)rel * 256 + tid) * 8;
    floatx4 v0 = *(const floatx4*)(src + base);
    floatx4 v1 = *(const floatx4*)(src + base + 4);
    bf16x8 o;
    #pragma unroll
    for (int j = 0; j < 4; j++){ o[j] = (__bf16)v0[j]; o[4 + j] = (__bf16)v1[j]; }
    *(bf16x8*)(dst + base) = o;
    return;
  }
  if (bid < 7424){                      // ---- weight transpose ----
    const int r = bid - 6656;
    const int z = r >> 8;
    const int h = (r >> 4) & 15, k0 = (r & 15) * 64;
    const float* src = (z == 0) ? w0 : (z == 1) ? w1 : w2;
    ushort* dst = (z == 0) ? t0 : (z == 1) ? t1 : t2;
    const int qd = tid >> 6, lo = tid & 63;
    #pragma unroll
    for (int i = 0; i < 16; i++){
      int kl = qd + i * 4;
      float f = src[((size_t)h * 1024 + k0 + kl) * 64 + lo];
      union { __bf16 h2; ushort u; } zz; zz.h2 = (__bf16)f;
      T[kl][lo] = zz.u;
    }
    __syncthreads();
    #pragma unroll
    for (int i = 0; i < 16; i++){
      int dk = qd + i * 4;
      dst[((size_t)h * 64 + dk) * 1024 + k0 + lo] = T[lo][dk];
    }
    return;
  }
  if (bid < 11520){                     // ---- mask pack ----
    const int r = bid - 7424;
    #pragma unroll
    for (int rep = 0; rep < 4; rep++){
      const int gid = r * 1024 + rep * 256 + tid;
      const int widx = gid >> 6;
      int m = M[(size_t)widx * 64 + (gid & 63)];
      unsigned long long bal = __ballot(m != 0);
      if ((gid & 63) == 0) MB[widx] = bal;
    }
    return;
  }
  // ---- zero BN partials ----
  *(floatx4*)(part + tid * 8) = f32x4{0.f, 0.f, 0.f, 0.f};
  *(floatx4*)(part + tid * 8 + 4) = f32x4{0.f, 0.f, 0.f, 0.f};
}

// ---------------------------------------------------------------------------
// K1: merged projections (z = 0:Q 1:K 2:V).  OUT bf16; z==2 writes transposed
// VT(hb,64,1024).  XOR bank swizzle; XCD-aware tile remap per z-slice.
// ---------------------------------------------------------------------------
__global__ __launch_bounds__(256) void k_projm(const ushort* __restrict__ qbp,
                                               const ushort* __restrict__ kbp,
                                               const ushort* __restrict__ vbp,
                                               const ushort* __restrict__ wqT,
                                               const ushort* __restrict__ wkT,
                                               const ushort* __restrict__ wvT,
                                               ushort* __restrict__ qh,
                                               ushort* __restrict__ kh,
                                               ushort* __restrict__ vt){
  __shared__ bf16x8 Ach[8 * 128];
  __shared__ bf16x8 Bch[8 * 128];
  const int z = blockIdx.z;
  const ushort* Xb = (z == 0) ? qbp : (z == 1) ? kbp : vbp;
  const ushort* WT = (z == 0) ? wqT : (z == 1) ? wkT : wvT;
  const int tid = threadIdx.x;
  const int lane = tid & 63, wid = tid >> 6;
  const int g = lane >> 4, c = lane & 15;
  const int d = blockIdx.y * 8 + blockIdx.x;
  const int tile = (d & 7) * 32 + (d >> 3);
  const int row0 = (tile >> 3) * 128, col0 = (tile & 7) * 128;
  const int wm = (wid >> 1) * 64, wn = (wid & 1) * 64;

  f32x4 zero = {0.f, 0.f, 0.f, 0.f};
  f32x4 acc[4][4];
  #pragma unroll
  for (int i = 0; i < 4; i++)
    #pragma unroll
    for (int j = 0; j < 4; j++) acc[i][j] = zero;

  for (int k0 = 0; k0 < ND; k0 += 64){
    #pragma unroll
    for (int i = 0; i < 4; i++){
      int e = tid + i * 256;
      int kc = e & 7, m = e >> 3;
      Ach[kc * 128 + (m ^ kc)] = *(const bf16x8*)(Xb + (size_t)(row0 + m) * ND + k0 + kc * 8);
    }
    #pragma unroll
    for (int i = 0; i < 4; i++){
      int e = tid + i * 256;
      int kc = e & 7, n = e >> 3;
      int hh = (col0 + n) >> 6, dk = (col0 + n) & 63;
      Bch[kc * 128 + (n ^ kc)] = *(const bf16x8*)(WT + ((size_t)(hh << 6) + dk) * 1024 + k0 + kc * 8);
    }
    __syncthreads();
    bf16x8 bfr[4][2];
    #pragma unroll
    for (int ni = 0; ni < 4; ni++){
      int n = wn + ni * 16 + c;
      bfr[ni][0] = Bch[g * 128 + (n ^ g)];
      bfr[ni][1] = Bch[(4 + g) * 128 + (n ^ (4 + g))];
    }
    #pragma unroll
    for (int mi = 0; mi < 4; mi++){
      int m = wm + mi * 16 + c;
      bf16x8 a0 = Ach[g * 128 + (m ^ g)];
      bf16x8 a1 = Ach[(4 + g) * 128 + (m ^ (4 + g))];
      #pragma unroll
      for (int ni = 0; ni < 4; ni++){
        acc[mi][ni] = MFMA(a0, bfr[ni][0], acc[mi][ni]);
        acc[mi][ni] = MFMA(a1, bfr[ni][1], acc[mi][ni]);
      }
    }
    __syncthreads();
  }
  if (z == 2){
    // transposed epilogue: VT[(hh*NB+bb)*64 + dk][l], 8B vector stores
    #pragma unroll
    for (int mi = 0; mi < 4; mi++){
      #pragma unroll
      for (int ni = 0; ni < 4; ni++){
        int n = col0 + wn + ni * 16 + c;
        int hh = n >> 6, dk = n & 63;
        int m0 = row0 + wm + mi * 16 + g * 4;
        int bb = m0 >> 10, l = m0 & 1023;
        B4 o;
        #pragma unroll
        for (int r = 0; r < 4; r++) o.v[r] = (__bf16)acc[mi][ni][r];
        *(unsigned long long*)(vt + (((size_t)hh * NB + bb) * 64 + dk) * 1024 + l) = o.ll;
      }
    }
  } else {
    ushort* OUT = (z == 0) ? qh : kh;
    #pragma unroll
    for (int mi = 0; mi < 4; mi++){
      #pragma unroll
      for (int ni = 0; ni < 4; ni++){
        #pragma unroll
        for (int r = 0; r < 4; r++){
          int m = row0 + wm + mi * 16 + g * 4 + r;
          int n = col0 + wn + ni * 16 + c;
          int bb = m >> 10, ls = m & 1023;
          int hh = n >> 6, dk = n & 63;
          st_bf(OUT + (((size_t)hh * NB + bb) * NL + ls) * NDK + dk, acc[mi][ni][r]);
        }
      }
    }
  }
}

// ---------------------------------------------------------------------------
// K2: fused attention (swapped QK^T), two passes; K and V LDS-staged with XOR
// swizzle (V from transposed VT -> coalesced vector staging); mask in LDS.
// ---------------------------------------------------------------------------
__global__ __launch_bounds__(256, 4) void k_attn(const ushort* __restrict__ QH,
                                                 const ushort* __restrict__ KH,
                                                 const ushort* __restrict__ VT,
                                                 const unsigned* __restrict__ MB,
                                                 float* __restrict__ ATT,
                                                 ushort* __restrict__ CTX){
  __shared__ bf16x8 Kch[512];        // [sr][kc^(sr&7)]
  __shared__ bf16x8 Vch[512];        // [kc][dv^kc]
  __shared__ ushort Ps[4][16][72];
  __shared__ unsigned Ms[64 * 33];
  const int tid = threadIdx.x;
  const int lane = tid & 63, wid = tid >> 6;
  const int g = lane >> 4, c = lane & 15;
  const int d = blockIdx.y * 16 + blockIdx.x;
  const int tile = (d & 7) * 128 + (d >> 3);
  const int hb = tile >> 4;
  const int q0 = (tile & 15) * 64;
  const int h = hb >> 2, b = hb & 3;

  const int q = q0 + wid * 16 + c;
  const size_t qkbase = (size_t)hb * NL;

  bf16x8 qf0 = *(const bf16x8*)(QH + (qkbase + q) * NDK + g * 8);
  bf16x8 qf1 = *(const bf16x8*)(QH + (qkbase + q) * NDK + 32 + g * 8);

  {
    const unsigned* mbase = MB + ((size_t)(b << 10) + q0) * 32;
    #pragma unroll
    for (int i = 0; i < 8; i++){
      int idx = tid + i * 256;
      int ql2 = idx >> 5, word = idx & 31;
      Ms[ql2 * 33 + word] = mbase[ql2 * 32 + word];
    }
  }
  const int ql = wid * 16 + c;
  const int mg = g * 4;

  // ---- pass 1: denominators ----
  float rs = 0.f;
  for (int t = 0; t < 16; ++t){
    __syncthreads();
    const ushort* ksrc = KH + (qkbase + t * 64) * NDK;
    #pragma unroll
    for (int i = 0; i < 2; i++){
      int idx = tid * 2 + i;
      int sr = idx >> 3, kc = idx & 7;
      Kch[sr * 8 + (kc ^ (sr & 7))] = *(const bf16x8*)(ksrc + idx * 8);
    }
    __syncthreads();
    #pragma unroll
    for (int sub2 = 0; sub2 < 4; ++sub2){
      int s = sub2 * 16 + c;
      bf16x8 kf0 = Kch[s * 8 + (g ^ (s & 7))];
      bf16x8 kf1 = Kch[s * 8 + ((4 + g) ^ (s & 7))];
      f32x4 a = {0.f, 0.f, 0.f, 0.f};
      a = MFMA(kf0, qf0, a);
      a = MFMA(kf1, qf1, a);
      unsigned w = Ms[ql * 33 + t * 2 + (sub2 >> 1)];
      unsigned bits4 = (w >> (((sub2 & 1) << 4) + mg)) & 0xFu;
      #pragma unroll
      for (int r = 0; r < 4; r++)
        rs += ((bits4 >> r) & 1u) ? 0.f : __expf(a[r] * (1.f / 32.f));
    }
  }
  rs += __shfl_xor(rs, 16);
  rs += __shfl_xor(rs, 32);
  const float invd = 1.f / rs;

  // ---- pass 2: attns write + PV ----
  f32x4 zero = {0.f, 0.f, 0.f, 0.f};
  f32x4 acc[4];
  #pragma unroll
  for (int i = 0; i < 4; i++) acc[i] = zero;

  for (int t = 0; t < 16; ++t){
    __syncthreads();
    const ushort* ksrc = KH + (qkbase + t * 64) * NDK;
    #pragma unroll
    for (int i = 0; i < 2; i++){
      int idx = tid * 2 + i;
      int sr = idx >> 3, kc = idx & 7;
      Kch[sr * 8 + (kc ^ (sr & 7))] = *(const bf16x8*)(ksrc + idx * 8);
    }
    #pragma unroll
    for (int i = 0; i < 2; i++){
      int idx = tid + i * 256;
      int dv = idx >> 3, kc = idx & 7;
      Vch[kc * 64 + (dv ^ kc)] = *(const bf16x8*)(VT + ((size_t)hb * 64 + dv) * 1024 + t * 64 + kc * 8);
    }
    __syncthreads();
    #pragma unroll
    for (int sub2 = 0; sub2 < 4; ++sub2){
      int s = sub2 * 16 + c;
      bf16x8 kf0 = Kch[s * 8 + (g ^ (s & 7))];
      bf16x8 kf1 = Kch[s * 8 + ((4 + g) ^ (s & 7))];
      f32x4 a = {0.f, 0.f, 0.f, 0.f};
      a = MFMA(kf0, qf0, a);
      a = MFMA(kf1, qf1, a);
      unsigned w = Ms[ql * 33 + t * 2 + (sub2 >> 1)];
      unsigned bits4 = (w >> (((sub2 & 1) << 4) + mg)) & 0xFu;
      floatx4 pn;
      B4 pw;
      #pragma unroll
      for (int r = 0; r < 4; r++){
        float p = ((bits4 >> r) & 1u) ? 0.f : __expf(a[r] * (1.f / 32.f)) * invd;
        pn[r] = p;
        pw.v[r] = (__bf16)p;
      }
      *(floatx4*)(ATT + ((size_t)hb * NL + q) * NL + (t * 4 + sub2) * 16 + g * 4) = pn;
      *(unsigned long long*)&Ps[wid][c][sub2 * 16 + g * 4] = pw.ll;
    }
    #pragma unroll
    for (int ss = 0; ss < 2; ++ss){
      bf16x8 afr = *(bf16x8*)&Ps[wid][c][ss * 32 + g * 8];
      #pragma unroll
      for (int ni = 0; ni < 4; ni++){
        int kcr = ss * 4 + g;
        bf16x8 vfr = Vch[kcr * 64 + ((ni * 16 + c) ^ kcr)];
        acc[ni] = MFMA(afr, vfr, acc[ni]);
      }
    }
  }

  #pragma unroll
  for (int ni = 0; ni < 4; ni++)
    #pragma unroll
    for (int r = 0; r < 4; r++){
      int qq = q0 + wid * 16 + g * 4 + r;
      int dv = ni * 16 + c;
      st_bf(CTX + ((size_t)b * NL + qq) * ND + h * NDK + dv, acc[ni][r]);
    }
}

// ---------------------------------------------------------------------------
// K4: output projection + bias + residual + fused BN partial sums (atomics)
// ---------------------------------------------------------------------------
__global__ __launch_bounds__(256) void k_projo(const ushort* __restrict__ CTX,
                                               const ushort* __restrict__ PWb,
                                               const float* __restrict__ PB,
                                               const float* __restrict__ RES,
                                               float* __restrict__ X,
                                               float* __restrict__ part){
  __shared__ bf16x8 Ach[8 * 128];
  __shared__ bf16x8 Bch[8 * 128];
  const int tid = threadIdx.x;
  const int lane = tid & 63, wid = tid >> 6;
  const int g = lane >> 4, c = lane & 15;
  const int d = blockIdx.y * 8 + blockIdx.x;
  const int tile = (d & 7) * 32 + (d >> 3);
  const int row0 = (tile >> 3) * 128, col0 = (tile & 7) * 128;
  const int wm = (wid >> 1) * 64, wn = (wid & 1) * 64;

  f32x4 zero = {0.f, 0.f, 0.f, 0.f};
  f32x4 acc[4][4];
  #pragma unroll
  for (int i = 0; i < 4; i++)
    #pragma unroll
    for (int j = 0; j < 4; j++) acc[i][j] = zero;

  for (int k0 = 0; k0 < ND; k0 += 64){
    #pragma unroll
    for (int i = 0; i < 4; i++){
      int e = tid + i * 256;
      int kc = e & 7, m = e >> 3;
      Ach[kc * 128 + (m ^ kc)] = *(const bf16x8*)(CTX + (size_t)(row0 + m) * ND + k0 + kc * 8);
    }
    #pragma unroll
    for (int i = 0; i < 4; i++){
      int e = tid + i * 256;
      int kc = e & 7, n = e >> 3;
      Bch[kc * 128 + (n ^ kc)] = *(const bf16x8*)(PWb + (size_t)(col0 + n) * 1024 + k0 + kc * 8);
    }
    __syncthreads();
    bf16x8 bfr[4][2];
    #pragma unroll
    for (int ni = 0; ni < 4; ni++){
      int n = wn + ni * 16 + c;
      bfr[ni][0] = Bch[g * 128 + (n ^ g)];
      bfr[ni][1] = Bch[(4 + g) * 128 + (n ^ (4 + g))];
    }
    #pragma unroll
    for (int mi = 0; mi < 4; mi++){
      int m = wm + mi * 16 + c;
      bf16x8 a0 = Ach[g * 128 + (m ^ g)];
      bf16x8 a1 = Ach[(4 + g) * 128 + (m ^ (4 + g))];
      #pragma unroll
      for (int ni = 0; ni < 4; ni++){
        acc[mi][ni] = MFMA(a0, bfr[ni][0], acc[mi][ni]);
        acc[mi][ni] = MFMA(a1, bfr[ni][1], acc[mi][ni]);
      }
    }
    __syncthreads();
  }
  float s_[4] = {0.f, 0.f, 0.f, 0.f}, s2_[4] = {0.f, 0.f, 0.f, 0.f};
  #pragma unroll
  for (int mi = 0; mi < 4; mi++)
    #pragma unroll
    for (int ni = 0; ni < 4; ni++)
      #pragma unroll
      for (int r = 0; r < 4; r++){
        int m = row0 + wm + mi * 16 + g * 4 + r;
        int n = col0 + wn + ni * 16 + c;
        float val = acc[mi][ni][r] + PB[n] + RES[(size_t)m * ND + n];
        X[(size_t)m * ND + n] = val;
        s_[ni] += val; s2_[ni] += val * val;
      }
  #pragma unroll
  for (int ni = 0; ni < 4; ni++){
    float a = s_[ni], b2 = s2_[ni];
    a += __shfl_xor(a, 16); b2 += __shfl_xor(b2, 16);
    a += __shfl_xor(a, 32); b2 += __shfl_xor(b2, 32);
    if (g == 0){
      int n = col0 + wn + ni * 16 + c;
      atomicAdd(&part[n], a);
      atomicAdd(&part[1024 + n], b2);
    }
  }
}

// ---------------------------------------------------------------------------
// K5: BN stats finalize + apply in place
// ---------------------------------------------------------------------------
__global__ __launch_bounds__(256) void k_bnst2(const float* __restrict__ part,
                                               float* __restrict__ MV){
  const int cx = blockIdx.x * 256 + threadIdx.x;
  float s = part[cx], s2 = part[1024 + cx];
  float mean = s * (1.f / (NB * NL));
  float var = s2 * (1.f / (NB * NL)) - mean * mean;
  MV[cx] = mean;
  MV[ND + cx] = rsqrtf(var + 1e-5f);
}

__global__ __launch_bounds__(256) void k_bnapply(float* __restrict__ X,
                                                 const float* __restrict__ MV,
                                                 const float* __restrict__ G,
                                                 const float* __restrict__ Bt){
  const int idx = blockIdx.x * 256 + threadIdx.x;
  const size_t base = (size_t)idx * 8;
  const int d0 = (int)(base & (ND - 1));
  floatx4 x0 = *(const floatx4*)(X + base);
  floatx4 x1 = *(const floatx4*)(X + base + 4);
  floatx4 o0, o1;
  #pragma unroll
  for (int e = 0; e < 4; e++){
    int d = d0 + e;
    o0[e] = (x0[e] - MV[d]) * MV[ND + d] * G[d] + Bt[d];
    int d2 = d0 + 4 + e;
    o1[e] = (x1[e] - MV[d2]) * MV[ND + d2] * G[d2] + Bt[d2];
  }
  *(floatx4*)(X + base) = o0;
  *(floatx4*)(X + base + 4) = o1;
}

// ---------------------------------------------------------------------------
extern "C" void kernel_launch(void* const* d_in, const int* in_sizes, int n_in,
                              void* d_out, int out_size, void* d_ws, size_t ws_size,
                              hipStream_t stream){
  const float* q      = (const float*)d_in[0];
  const float* k      = (const float*)d_in[1];
  const float* v      = (const float*)d_in[2];
  const int*   mask   = (const int*)d_in[3];
  const float* w_qs   = (const float*)d_in[4];
  const float* w_ks   = (const float*)d_in[5];
  const float* w_vs   = (const float*)d_in[6];
  const float* proj_w = (const float*)d_in[7];
  const float* proj_b = (const float*)d_in[8];
  const float* gamma  = (const float*)d_in[9];
  const float* beta   = (const float*)d_in[10];

  float* out_x   = (float*)d_out;
  float* out_att = out_x + (size_t)NB * NL * ND;

  char* ws = (char*)d_ws;
  ushort* qb  = (ushort*)(ws);                       // 8 MB (reused as ctx)
  ushort* kb  = (ushort*)(ws + (8u  << 20));
  ushort* vb  = (ushort*)(ws + (16u << 20));
  ushort* qh  = (ushort*)(ws + (24u << 20));
  ushort* kh  = (ushort*)(ws + (32u << 20));
  ushort* vt  = (ushort*)(ws + (40u << 20));         // transposed V
  ushort* wqT = (ushort*)(ws + (48u << 20));         // 2 MB each
  ushort* wkT = (ushort*)(ws + (50u << 20));
  ushort* wvT = (ushort*)(ws + (52u << 20));
  ushort* pwb = (ushort*)(ws + (54u << 20));
  unsigned long long* mb = (unsigned long long*)(ws + (56u << 20));  // 512 KB
  float*  part = (float*)(ws + (57u << 20));         // 8 KB
  float*  mv   = (float*)(ws + (58u << 20));         // 8 KB
  ushort* ctx  = qb;                                 // qb dead after projm

  dim3 blk(256);
  k_prep<<<dim3(11521), blk, 0, stream>>>(q, k, v, proj_w, w_qs, w_ks, w_vs, mask,
                                          qb, kb, vb, pwb, wqT, wkT, wvT, mb, part);
  k_projm<<<dim3(8, 32, 3), blk, 0, stream>>>(qb, kb, vb, wqT, wkT, wvT, qh, kh, vt);
  k_attn<<<dim3(16, 64), blk, 0, stream>>>(qh, kh, vt, (const unsigned*)mb, out_att, ctx);
  k_projo<<<dim3(8, 32), blk, 0, stream>>>(ctx, pwb, proj_b, q, out_x, part);
  k_bnst2<<<dim3(4), blk, 0, stream>>>(part, mv);
  k_bnapply<<<dim3(NB * NL * ND / 8 / 256), blk, 0, stream>>>(out_x, mv, gamma, beta);
}